// Round 10
// baseline (886.724 us; speedup 1.0000x reference)
//
#include <hip/hip_runtime.h>

#define D_MODEL   1024
#define D_HIDDEN  4096
#define N_EXPERTS 8
#define N_TOKENS  8192
#define NASSIGN   (N_TOKENS * 2)               // 16384
#define PADCAP    (NASSIGN + N_EXPERTS * 256)  // 18432 (256-aligned segments)
#define RT_TILES  (PADCAP / 256)               // 72

typedef unsigned short u16;
typedef __bf16 bf16x8 __attribute__((ext_vector_type(8)));
typedef float  f32x4  __attribute__((ext_vector_type(4)));

__device__ __forceinline__ u16 f2bf(float f) {
  union { float f; unsigned u; } c; c.f = f;
  unsigned u = c.u;
  u = (u + 0x7fffu + ((u >> 16) & 1u)) >> 16;   // RNE
  return (u16)u;
}

__device__ __forceinline__ void async16(const void* g, void* l) {
  __builtin_amdgcn_global_load_lds(
      (const __attribute__((address_space(1))) unsigned int*)g,
      (__attribute__((address_space(3))) unsigned int*)l, 16, 0, 0);
}

#define MFMA(a, b, c) __builtin_amdgcn_mfma_f32_16x16x32_bf16((a), (b), (c), 0, 0, 0)

// Barriers carry an asm "memory" clobber: LDS/global memory ops cannot be
// scheduled across them (correctness for gload_lds->ds_read ordering), but
// NO sched_barrier(0) — m141: order-pinning defeats the scheduler (1.7x).
#define WAIT8_BARRIER() asm volatile("s_waitcnt vmcnt(8)\n\ts_barrier" ::: "memory")
#define WAIT0_BARRIER() asm volatile("s_waitcnt vmcnt(0)\n\ts_barrier" ::: "memory")
#define BARRIER()       asm volatile("s_barrier" ::: "memory")

// ---------------- gating: 1 wave per token, 4 tokens per block ----------------
__global__ __launch_bounds__(256) void gating_kernel(
    const float* __restrict__ x, const float* __restrict__ gw,
    const float* __restrict__ gb, int* __restrict__ counts,
    int* __restrict__ tok_idx, float* __restrict__ tok_w)
{
  const int n = blockIdx.x * 4 + (threadIdx.x >> 6);
  const int lane = threadIdx.x & 63;
  float acc[8] = {0.f,0.f,0.f,0.f,0.f,0.f,0.f,0.f};
  for (int d = lane; d < D_MODEL; d += 64) {
    float xv = x[(size_t)n * D_MODEL + d];
    const float4* g = (const float4*)&gw[d * 8];
    float4 g0 = g[0], g1 = g[1];
    acc[0] += xv * g0.x; acc[1] += xv * g0.y; acc[2] += xv * g0.z; acc[3] += xv * g0.w;
    acc[4] += xv * g1.x; acc[5] += xv * g1.y; acc[6] += xv * g1.z; acc[7] += xv * g1.w;
  }
  for (int off = 32; off; off >>= 1)
    #pragma unroll
    for (int e = 0; e < 8; ++e) acc[e] += __shfl_xor(acc[e], off, 64);
  if (lane == 0) {
    float l[8], p[8];
    float m = -1e30f;
    for (int e = 0; e < 8; ++e) { l[e] = acc[e] + gb[e]; m = fmaxf(m, l[e]); }
    float s = 0.f;
    for (int e = 0; e < 8; ++e) { p[e] = expf(l[e] - m); s += p[e]; }
    float inv = 1.f / s;
    for (int e = 0; e < 8; ++e) p[e] *= inv;
    int i0 = 0;
    for (int e = 1; e < 8; ++e) if (p[e] > p[i0]) i0 = e;          // ties -> lowest idx
    int i1 = (i0 == 0) ? 1 : 0;
    for (int e = 0; e < 8; ++e) if (e != i0 && p[e] > p[i1]) i1 = e;
    tok_idx[2 * n]     = i0;  tok_idx[2 * n + 1] = i1;
    tok_w[2 * n]       = p[i0]; tok_w[2 * n + 1] = p[i1];
    atomicAdd(&counts[i0], 1);
    atomicAdd(&counts[i1], 1);
  }
}

// ---------------- offsets (256-aligned) + load-balancing loss ----------------
__global__ void finalize_routing(const int* __restrict__ counts,
                                 int* __restrict__ offsets,
                                 float* __restrict__ out_loss)
{
  int off = 0;
  for (int e = 0; e < 8; ++e) {
    offsets[e] = off;
    off += ((counts[e] + 255) >> 8) << 8;   // 256-align each expert segment
  }
  offsets[8] = off;
  float loss = 0.f;
  for (int e = 0; e < 8; ++e) {
    float f = (float)counts[e] * (1.f / (float)NASSIGN);
    loss += f * f;
  }
  *out_loss = loss;
}

// ---------------- scatter tokens to expert segments ----------------
__global__ __launch_bounds__(256) void scatter_kernel(
    const int* __restrict__ tok_idx, const float* __restrict__ tok_w,
    const int* __restrict__ offsets, int* __restrict__ cursors,
    int* __restrict__ assign_token, float* __restrict__ assign_w,
    int* __restrict__ tok_pos)
{
  const int n = blockIdx.x * 256 + threadIdx.x;
  #pragma unroll
  for (int k = 0; k < 2; ++k) {
    int e = tok_idx[n * 2 + k];
    int pos = offsets[e] + atomicAdd(&cursors[e], 1);
    assign_token[pos] = n;
    assign_w[pos] = tok_w[n * 2 + k];
    tok_pos[n * 2 + k] = pos;
  }
}

// ---------------- x fp32 -> bf16 ----------------
__global__ __launch_bounds__(256) void convert_x_kernel(
    const float* __restrict__ x, u16* __restrict__ xb)
{
  size_t i = ((size_t)blockIdx.x * 256 + threadIdx.x) * 4;
  float4 v = *(const float4*)&x[i];
  unsigned lo = (unsigned)f2bf(v.x) | ((unsigned)f2bf(v.y) << 16);
  unsigned hi = (unsigned)f2bf(v.z) | ((unsigned)f2bf(v.w) << 16);
  uint2 o; o.x = lo; o.y = hi;
  *(uint2*)&xb[i] = o;
}

// ---------------- transpose+convert: in[e][R][C] fp32 -> out[e][C][R] bf16 ----------------
__global__ __launch_bounds__(256) void transpose_cvt_kernel(
    const float* __restrict__ in, u16* __restrict__ out, int R, int C)
{
  const int e = blockIdx.z;
  const int c0 = blockIdx.x * 32, r0 = blockIdx.y * 32;
  __shared__ float tile[32][33];
  const int tx = threadIdx.x & 31, ty = threadIdx.x >> 5;
  const float* ip = in + (size_t)e * R * C;
  u16* op = out + (size_t)e * R * C;
  #pragma unroll
  for (int i = 0; i < 4; ++i)
    tile[ty + i * 8][tx] = ip[(size_t)(r0 + ty + i * 8) * C + c0 + tx];
  __syncthreads();
  #pragma unroll
  for (int i = 0; i < 4; ++i)
    op[(size_t)(c0 + ty + i * 8) * R + r0 + tx] = f2bf(tile[tx][ty + i * 8]);
}

// ================== 4-phase GEMM core (both GEMMs) ==================
// BM=BN=256, BK=64. 512 threads = 8 waves (2M x 4N), wave-tile 128x64, acc[8][4].
// LDS 128KB: per operand 2dbuf x 2khalf regions of [256 rows][32 k] bf16 (8192 u16).
// Region layout: [row][4 slots of 16B], slot swizzled s^=((row>>1)&3) (conflict-free).
// vmcnt(8) leaves the 2 newest 4-load groups in flight; waits only for the
// group actually consumed this phase (m135 oldest-first semantics).

// ---------------- GEMM1: h = relu(X_gathered @ w1[e] + b1[e]) ----------------
__global__ __launch_bounds__(512, 2) void gemm1_kernel(
    const u16* __restrict__ xb, const u16* __restrict__ w1t,
    const float* __restrict__ b1, const int* __restrict__ assign_token,
    const int* __restrict__ offsets, u16* __restrict__ hbuf)
{
  const int rtl = (blockIdx.x & 7) * 9 + (blockIdx.x >> 3);   // XCD-bijective (72=8*9)
  const int ct = blockIdx.y;                                   // 0..15
  if (rtl * 256 >= offsets[8]) return;
  int e = 0;
  while (offsets[e + 1] <= rtl * 256) ++e;

  __shared__ __align__(16) u16 smem[65536];   // 128 KB

  const int tid = threadIdx.x;
  const int wave = tid >> 6, lane = tid & 63;
  const int wm = wave >> 2, wn = wave & 3;

  // staging: chunk c -> row=c>>2, slot=c&3; src slot = slot^((row>>1)&3)
  const int r0 = tid >> 2, s0 = (tid & 3) ^ ((r0 >> 1) & 3);
  const int r1 = r0 + 128, s1 = (tid & 3) ^ ((r1 >> 1) & 3);
  const long aS0 = (long)assign_token[rtl * 256 + r0] * D_MODEL + s0 * 8;
  const long aS1 = (long)assign_token[rtl * 256 + r1] * D_MODEL + s1 * 8;
  const long bS0 = ((long)e * D_HIDDEN + ct * 256 + r0) * D_MODEL + s0 * 8;
  const long bS1 = ((long)e * D_HIDDEN + ct * 256 + r1) * D_MODEL + s1 * 8;

  f32x4 acc[8][4];
  #pragma unroll
  for (int i = 0; i < 8; ++i)
    #pragma unroll
    for (int j = 0; j < 4; ++j) acc[i][j] = (f32x4){0.f, 0.f, 0.f, 0.f};

  int aoff[8], boff[4];
  #pragma unroll
  for (int f = 0; f < 8; ++f) {
    int row = wm * 128 + f * 16 + (lane & 15);
    aoff[f] = row * 32 + (((lane >> 4) ^ ((row >> 1) & 3)) * 8);
  }
  #pragma unroll
  for (int f = 0; f < 4; ++f) {
    int col = wn * 64 + f * 16 + (lane & 15);
    boff[f] = 32768 + col * 32 + (((lane >> 4) ^ ((col >> 1) & 3)) * 8);
  }

  #define STG1(d, h, koff) do { \
    u16* A_ = &smem[((d) * 2 + (h)) * 8192 + wave * 512]; \
    u16* B_ = &smem[32768 + ((d) * 2 + (h)) * 8192 + wave * 512]; \
    async16(xb  + aS0 + (koff), A_); \
    async16(xb  + aS1 + (koff), A_ + 4096); \
    async16(w1t + bS0 + (koff), B_); \
    async16(w1t + bS1 + (koff), B_ + 4096); \
  } while (0)

  const int NT = D_MODEL / 64;   // 16
  STG1(0, 0, 0);       // klo(0)
  STG1(0, 1, 32);      // khi(0)
  STG1(1, 0, 64);      // klo(1)

  for (int t = 0; t < NT; ++t) {
    const int d = t & 1;
    const int reg0 = d * 16384, reg1 = d * 16384 + 8192;
    bf16x8 a[8], b0, b1r;
    // ---- p0: kk=0, cols 0..31   (needs klo(t))
    if (t + 1 < NT) WAIT8_BARRIER();
    else            WAIT0_BARRIER();
    #pragma unroll
    for (int f = 0; f < 8; ++f) a[f] = *(const bf16x8*)&smem[reg0 + aoff[f]];
    b0 = *(const bf16x8*)&smem[reg0 + boff[0]];
    b1r = *(const bf16x8*)&smem[reg0 + boff[1]];
    if (t + 1 < NT) STG1(d ^ 1, 1, (t + 1) * 64 + 32);   // khi(t+1)
    __builtin_amdgcn_s_setprio(1);
    #pragma unroll
    for (int f = 0; f < 8; ++f) {
      acc[f][0] = MFMA(a[f], b0, acc[f][0]);
      acc[f][1] = MFMA(a[f], b1r, acc[f][1]);
    }
    __builtin_amdgcn_s_setprio(0);
    // ---- p1: kk=0, cols 32..63
    BARRIER();
    b0 = *(const bf16x8*)&smem[reg0 + boff[2]];
    b1r = *(const bf16x8*)&smem[reg0 + boff[3]];
    __builtin_amdgcn_s_setprio(1);
    #pragma unroll
    for (int f = 0; f < 8; ++f) {
      acc[f][2] = MFMA(a[f], b0, acc[f][2]);
      acc[f][3] = MFMA(a[f], b1r, acc[f][3]);
    }
    __builtin_amdgcn_s_setprio(0);
    // ---- p2: kk=1, cols 0..31   (needs khi(t))
    if (t + 1 < NT) WAIT8_BARRIER();
    else            WAIT0_BARRIER();
    #pragma unroll
    for (int f = 0; f < 8; ++f) a[f] = *(const bf16x8*)&smem[reg1 + aoff[f]];
    b0 = *(const bf16x8*)&smem[reg1 + boff[0]];
    b1r = *(const bf16x8*)&smem[reg1 + boff[1]];
    if (t + 2 < NT) STG1(d, 0, (t + 2) * 64);            // klo(t+2)
    __builtin_amdgcn_s_setprio(1);
    #pragma unroll
    for (int f = 0; f < 8; ++f) {
      acc[f][0] = MFMA(a[f], b0, acc[f][0]);
      acc[f][1] = MFMA(a[f], b1r, acc[f][1]);
    }
    __builtin_amdgcn_s_setprio(0);
    // ---- p3: kk=1, cols 32..63
    BARRIER();
    b0 = *(const bf16x8*)&smem[reg1 + boff[2]];
    b1r = *(const bf16x8*)&smem[reg1 + boff[3]];
    __builtin_amdgcn_s_setprio(1);
    #pragma unroll
    for (int f = 0; f < 8; ++f) {
      acc[f][2] = MFMA(a[f], b0, acc[f][2]);
      acc[f][3] = MFMA(a[f], b1r, acc[f][3]);
    }
    __builtin_amdgcn_s_setprio(0);
  }
  #undef STG1

  float bias[4];
  #pragma unroll
  for (int j = 0; j < 4; ++j)
    bias[j] = b1[(size_t)e * D_HIDDEN + ct * 256 + wn * 64 + j * 16 + (lane & 15)];

  __syncthreads();
  // Hs overlay: 256x256 bf16 = 128 KB = exactly smem
  u16* Hs = smem;
  #pragma unroll
  for (int i = 0; i < 8; ++i)
    #pragma unroll
    for (int j = 0; j < 4; ++j)
      #pragma unroll
      for (int r = 0; r < 4; ++r) {
        int rl = wm * 128 + i * 16 + ((lane >> 4) * 4) + r;
        int cl = wn * 64 + j * 16 + (lane & 15);
        Hs[rl * 256 + cl] = f2bf(fmaxf(acc[i][j][r] + bias[j], 0.f));
      }
  __syncthreads();
  // 256 rows x 32 chunks of 16B
  #pragma unroll
  for (int it = 0; it < 16; ++it) {
    int cc = tid + it * 512;
    int row = cc >> 5, cs = cc & 31;
    *(uint4*)&hbuf[((size_t)(rtl * 256 + row)) * D_HIDDEN + ct * 256 + cs * 8] =
        *(const uint4*)&Hs[row * 256 + cs * 8];
  }
}

// ---------------- GEMM2 (split-K=4): dst += w * (h @ w2[e] [+ b2 at sk0]) ----------------
template <bool EO>
__global__ __launch_bounds__(512, 2) void gemm2_kernel(
    const u16* __restrict__ hbuf, const u16* __restrict__ w2t,
    const float* __restrict__ b2, const int* __restrict__ assign_token,
    const float* __restrict__ assign_w, const int* __restrict__ offsets,
    float* __restrict__ dst)   // EO ? eo buffer (by pos) : out (by token)
{
  const int rtl = (blockIdx.x & 7) * 9 + (blockIdx.x >> 3);
  const int ct = blockIdx.y;                 // 0..3
  const int sk = blockIdx.z;                 // 0..3
  const long skb = (long)sk * 1024;
  if (rtl * 256 >= offsets[8]) return;
  int e = 0;
  while (offsets[e + 1] <= rtl * 256) ++e;

  __shared__ __align__(16) u16 smem[65536];

  const int tid = threadIdx.x;
  const int wave = tid >> 6, lane = tid & 63;
  const int wm = wave >> 2, wn = wave & 3;

  const int r0 = tid >> 2, s0 = (tid & 3) ^ ((r0 >> 1) & 3);
  const int r1 = r0 + 128, s1 = (tid & 3) ^ ((r1 >> 1) & 3);
  const long aS0 = ((long)(rtl * 256 + r0)) * D_HIDDEN + s0 * 8;
  const long aS1 = ((long)(rtl * 256 + r1)) * D_HIDDEN + s1 * 8;
  const long bS0 = ((long)e * D_MODEL + ct * 256 + r0) * D_HIDDEN + s0 * 8;
  const long bS1 = ((long)e * D_MODEL + ct * 256 + r1) * D_HIDDEN + s1 * 8;

  f32x4 acc[8][4];
  #pragma unroll
  for (int i = 0; i < 8; ++i)
    #pragma unroll
    for (int j = 0; j < 4; ++j) acc[i][j] = (f32x4){0.f, 0.f, 0.f, 0.f};

  int aoff[8], boff[4];
  #pragma unroll
  for (int f = 0; f < 8; ++f) {
    int row = wm * 128 + f * 16 + (lane & 15);
    aoff[f] = row * 32 + (((lane >> 4) ^ ((row >> 1) & 3)) * 8);
  }
  #pragma unroll
  for (int f = 0; f < 4; ++f) {
    int col = wn * 64 + f * 16 + (lane & 15);
    boff[f] = 32768 + col * 32 + (((lane >> 4) ^ ((col >> 1) & 3)) * 8);
  }

  #define STG2(d, h, koff) do { \
    u16* A_ = &smem[((d) * 2 + (h)) * 8192 + wave * 512]; \
    u16* B_ = &smem[32768 + ((d) * 2 + (h)) * 8192 + wave * 512]; \
    async16(hbuf + aS0 + (koff), A_); \
    async16(hbuf + aS1 + (koff), A_ + 4096); \
    async16(w2t + bS0 + (koff), B_); \
    async16(w2t + bS1 + (koff), B_ + 4096); \
  } while (0)

  const int NT = 1024 / 64;   // 16
  STG2(0, 0, skb);
  STG2(0, 1, skb + 32);
  STG2(1, 0, skb + 64);

  for (int t = 0; t < NT; ++t) {
    const int d = t & 1;
    const int reg0 = d * 16384, reg1 = d * 16384 + 8192;
    bf16x8 a[8], b0, b1r;
    if (t + 1 < NT) WAIT8_BARRIER();
    else            WAIT0_BARRIER();
    #pragma unroll
    for (int f = 0; f < 8; ++f) a[f] = *(const bf16x8*)&smem[reg0 + aoff[f]];
    b0 = *(const bf16x8*)&smem[reg0 + boff[0]];
    b1r = *(const bf16x8*)&smem[reg0 + boff[1]];
    if (t + 1 < NT) STG2(d ^ 1, 1, skb + (t + 1) * 64 + 32);
    __builtin_amdgcn_s_setprio(1);
    #pragma unroll
    for (int f = 0; f < 8; ++f) {
      acc[f][0] = MFMA(a[f], b0, acc[f][0]);
      acc[f][1] = MFMA(a[f], b1r, acc[f][1]);
    }
    __builtin_amdgcn_s_setprio(0);
    BARRIER();
    b0 = *(const bf16x8*)&smem[reg0 + boff[2]];
    b1r = *(const bf16x8*)&smem[reg0 + boff[3]];
    __builtin_amdgcn_s_setprio(1);
    #pragma unroll
    for (int f = 0; f < 8; ++f) {
      acc[f][2] = MFMA(a[f], b0, acc[f][2]);
      acc[f][3] = MFMA(a[f], b1r, acc[f][3]);
    }
    __builtin_amdgcn_s_setprio(0);
    if (t + 1 < NT) WAIT8_BARRIER();
    else            WAIT0_BARRIER();
    #pragma unroll
    for (int f = 0; f < 8; ++f) a[f] = *(const bf16x8*)&smem[reg1 + aoff[f]];
    b0 = *(const bf16x8*)&smem[reg1 + boff[0]];
    b1r = *(const bf16x8*)&smem[reg1 + boff[1]];
    if (t + 2 < NT) STG2(d, 0, skb + (t + 2) * 64);
    __builtin_amdgcn_s_setprio(1);
    #pragma unroll
    for (int f = 0; f < 8; ++f) {
      acc[f][0] = MFMA(a[f], b0, acc[f][0]);
      acc[f][1] = MFMA(a[f], b1r, acc[f][1]);
    }
    __builtin_amdgcn_s_setprio(0);
    BARRIER();
    b0 = *(const bf16x8*)&smem[reg1 + boff[2]];
    b1r = *(const bf16x8*)&smem[reg1 + boff[3]];
    __builtin_amdgcn_s_setprio(1);
    #pragma unroll
    for (int f = 0; f < 8; ++f) {
      acc[f][2] = MFMA(a[f], b0, acc[f][2]);
      acc[f][3] = MFMA(a[f], b1r, acc[f][3]);
    }
    __builtin_amdgcn_s_setprio(0);
  }
  #undef STG2

  float bias[4];
  #pragma unroll
  for (int j = 0; j < 4; ++j)
    bias[j] = (sk == 0) ? b2[(size_t)e * D_MODEL + ct * 256 + wn * 64 + j * 16 + (lane & 15)] : 0.f;

  __syncthreads();
  float* wsm = (float*)smem;
  int* tsm = (int*)&smem[1024];
  if (tid < 256) {
    wsm[tid] = assign_w[rtl * 256 + tid];
    tsm[tid] = assign_token[rtl * 256 + tid];
  }
  __syncthreads();

  #pragma unroll
  for (int i = 0; i < 8; ++i)
    #pragma unroll
    for (int r = 0; r < 4; ++r) {
      int rl = wm * 128 + i * 16 + ((lane >> 4) * 4) + r;
      float wgt = wsm[rl];
      if (EO) {
        size_t row = (size_t)(rtl * 256 + rl);
        #pragma unroll
        for (int j = 0; j < 4; ++j) {
          float v = (acc[i][j][r] + bias[j]) * wgt;
          atomicAdd(&dst[row * D_MODEL + ct * 256 + wn * 64 + j * 16 + (lane & 15)], v);
        }
      } else {
        int tok = tsm[rl];
        #pragma unroll
        for (int j = 0; j < 4; ++j) {
          float v = (acc[i][j][r] + bias[j]) * wgt;
          atomicAdd(&dst[(size_t)tok * D_MODEL + ct * 256 + wn * 64 + j * 16 + (lane & 15)], v);
        }
      }
    }
}

// ---------------- combine: out[n] = eo[pos0] + eo[pos1] ----------------
__global__ __launch_bounds__(256) void combine_kernel(
    const float* __restrict__ eo, const int* __restrict__ tok_pos,
    float* __restrict__ out)
{
  int idx = blockIdx.x * 256 + threadIdx.x;   // one float4 per thread
  int n = idx >> 8;                           // 256 float4 per token
  int c = (idx & 255) * 4;
  int p0 = tok_pos[2 * n], p1 = tok_pos[2 * n + 1];
  float4 a = *(const float4*)&eo[(size_t)p0 * D_MODEL + c];
  float4 b = *(const float4*)&eo[(size_t)p1 * D_MODEL + c];
  float4 o; o.x = a.x + b.x; o.y = a.y + b.y; o.z = a.z + b.z; o.w = a.w + b.w;
  *(float4*)&out[(size_t)n * D_MODEL + c] = o;
}

// ---------------- fallback (tiny ws): naive fp32 per-assignment ----------------
__global__ __launch_bounds__(256) void moe_fallback_kernel(
    const float* __restrict__ x, const float* __restrict__ w1,
    const float* __restrict__ b1, const float* __restrict__ w2,
    const float* __restrict__ b2, const int* __restrict__ tok_idx,
    const float* __restrict__ tok_w, float* __restrict__ out)
{
  const int a = blockIdx.x;
  const int n = a >> 1, slot = a & 1;
  const int e = tok_idx[n * 2 + slot];
  const float wgt = tok_w[n * 2 + slot];
  __shared__ float xs[D_MODEL];
  __shared__ float hs[D_HIDDEN];
  const int tid = threadIdx.x;
  for (int d = tid; d < D_MODEL; d += 256) xs[d] = x[(size_t)n * D_MODEL + d];
  __syncthreads();
  for (int h = tid; h < D_HIDDEN; h += 256) {
    float acc = b1[(size_t)e * D_HIDDEN + h];
    for (int d = 0; d < D_MODEL; ++d)
      acc += xs[d] * w1[((size_t)e * D_MODEL + d) * D_HIDDEN + h];
    hs[h] = fmaxf(acc, 0.f);
  }
  __syncthreads();
  for (int d = tid; d < D_MODEL; d += 256) {
    float acc = b2[(size_t)e * D_MODEL + d];
    for (int h = 0; h < D_HIDDEN; ++h)
      acc += hs[h] * w2[((size_t)e * D_HIDDEN + h) * D_MODEL + d];
    atomicAdd(&out[(size_t)n * D_MODEL + d], wgt * acc);
  }
}

extern "C" void kernel_launch(void* const* d_in, const int* in_sizes, int n_in,
                              void* d_out, int out_size, void* d_ws, size_t ws_size,
                              hipStream_t stream) {
  const float* x      = (const float*)d_in[0];
  const float* gate_w = (const float*)d_in[1];
  const float* gate_b = (const float*)d_in[2];
  const float* w1     = (const float*)d_in[3];
  const float* b1     = (const float*)d_in[4];
  const float* w2     = (const float*)d_in[5];
  const float* b2     = (const float*)d_in[6];
  float* out = (float*)d_out;

  char* ws = (char*)d_ws;
  int*   counts       = (int*)(ws + 0);
  int*   cursors      = (int*)(ws + 32);
  int*   offsets      = (int*)(ws + 64);
  int*   tok_idx      = (int*)(ws + 256);       // 64 KB
  float* tok_w        = (float*)(ws + 65792);   // 64 KB
  int*   tok_pos      = (int*)(ws + 131328);    // 64 KB
  int*   assign_token = (int*)(ws + 196864);    // 72 KB (PADCAP ints)
  float* assign_w     = (float*)(ws + 270592);  // 72 KB
  const size_t X0 = 344320;
  // gemm1 live:  hbuf [X0, X0+144M) | xb [X0+144M, +16M) | w1t [X0+160M, +64M)
  // gemm2 live:  hbuf | w2t (aliases xb+w1t head) | eo [X0+208M, +72M) (aliases w1t tail)
  u16*   hbuf = (u16*)(ws + X0);
  u16*   xb   = (u16*)(ws + X0 + 150994944ull);
  u16*   w1t  = (u16*)(ws + X0 + 150994944ull + 16777216ull);
  u16*   w2t  = (u16*)(ws + X0 + 150994944ull);                 // 64 MB, dead xb+w1t
  float* eo   = (float*)(ws + X0 + 150994944ull + 67108864ull); // [PADCAP][1024] fp32
  const size_t REQ_FAST = X0 + 150994944ull + 16777216ull + 67108864ull; // ~224.8 MiB
  const size_t REQ_EO   = X0 + 150994944ull + 67108864ull + 75497472ull; // ~280.3 MiB

  const bool fast = (ws_size >= REQ_FAST);
  const bool eoPath = fast && (ws_size >= REQ_EO);

  // zero routing scratch (incl. pad entries of assign_* -> token 0, weight 0)
  hipMemsetAsync(ws, 0, X0, stream);
  if (!eoPath) {
    hipMemsetAsync(d_out, 0, (size_t)out_size * sizeof(float), stream);
  }

  gating_kernel<<<N_TOKENS / 4, 256, 0, stream>>>(x, gate_w, gate_b, counts, tok_idx, tok_w);
  finalize_routing<<<1, 1, 0, stream>>>(counts, offsets, out + (out_size - 1));

  if (fast) {
    scatter_kernel<<<N_TOKENS / 256, 256, 0, stream>>>(tok_idx, tok_w, offsets, cursors,
                                                       assign_token, assign_w, tok_pos);
    convert_x_kernel<<<(N_TOKENS * D_MODEL) / 1024, 256, 0, stream>>>(x, xb);
    transpose_cvt_kernel<<<dim3(D_HIDDEN / 32, D_MODEL / 32, N_EXPERTS), 256, 0, stream>>>(
        w1, w1t, D_MODEL, D_HIDDEN);
    gemm1_kernel<<<dim3(RT_TILES, D_HIDDEN / 256), 512, 0, stream>>>(
        xb, w1t, b1, assign_token, offsets, hbuf);
    transpose_cvt_kernel<<<dim3(D_MODEL / 32, D_HIDDEN / 32, N_EXPERTS), 256, 0, stream>>>(
        w2, w2t, D_HIDDEN, D_MODEL);
    if (eoPath) {
      // CRITICAL ORDER: eo overlaps w1t's tail; zero it only AFTER the w1t
      // transpose (last overlapping writer) is enqueued. (R7/R8 bug.)
      hipMemsetAsync(eo, 0, 75497472ull, stream);   // split-K accumulates atomically
      gemm2_kernel<true><<<dim3(RT_TILES, D_MODEL / 256, 4), 512, 0, stream>>>(
          hbuf, w2t, b2, assign_token, assign_w, offsets, eo);
      combine_kernel<<<(N_TOKENS * D_MODEL) / 1024, 256, 0, stream>>>(eo, tok_pos, out);
    } else {
      gemm2_kernel<false><<<dim3(RT_TILES, D_MODEL / 256, 4), 512, 0, stream>>>(
          hbuf, w2t, b2, assign_token, assign_w, offsets, out);
    }
  } else {
    moe_fallback_kernel<<<NASSIGN, 256, 0, stream>>>(x, w1, b1, w2, b2, tok_idx, tok_w, out);
  }
}

// Round 11
// 846.626 us; speedup vs baseline: 1.0474x; 1.0474x over previous
//
#include <hip/hip_runtime.h>

#define D_MODEL   1024
#define D_HIDDEN  4096
#define N_EXPERTS 8
#define N_TOKENS  8192
#define NASSIGN   (N_TOKENS * 2)               // 16384
#define PADCAP    (NASSIGN + N_EXPERTS * 256)  // 18432 (256-aligned segments)
#define RT_TILES  (PADCAP / 256)               // 72

typedef unsigned short u16;
typedef __bf16 bf16x8 __attribute__((ext_vector_type(8)));
typedef float  f32x4  __attribute__((ext_vector_type(4)));

__device__ __forceinline__ u16 f2bf(float f) {
  union { float f; unsigned u; } c; c.f = f;
  unsigned u = c.u;
  u = (u + 0x7fffu + ((u >> 16) & 1u)) >> 16;   // RNE
  return (u16)u;
}

__device__ __forceinline__ void async16(const void* g, void* l) {
  __builtin_amdgcn_global_load_lds(
      (const __attribute__((address_space(1))) unsigned int*)g,
      (__attribute__((address_space(3))) unsigned int*)l, 16, 0, 0);
}

#define MFMA(a, b, c) __builtin_amdgcn_mfma_f32_16x16x32_bf16((a), (b), (c), 0, 0, 0)

// asm "memory" clobber keeps memory ops on their source side of the barrier:
// ds_reads written BEFORE the barrier stay before it (latency hides under
// barrier arrival skew + other waves' MFMA — the m201 phase mechanism).
#define WAIT4_BARRIER() asm volatile("s_waitcnt vmcnt(4)\n\ts_barrier" ::: "memory")
#define WAIT0_BARRIER() asm volatile("s_waitcnt vmcnt(0)\n\ts_barrier" ::: "memory")
#define BARRIER()       asm volatile("s_barrier" ::: "memory")

// ---------------- gating: 1 wave per token, 4 tokens per block ----------------
__global__ __launch_bounds__(256) void gating_kernel(
    const float* __restrict__ x, const float* __restrict__ gw,
    const float* __restrict__ gb, int* __restrict__ counts,
    int* __restrict__ tok_idx, float* __restrict__ tok_w)
{
  const int n = blockIdx.x * 4 + (threadIdx.x >> 6);
  const int lane = threadIdx.x & 63;
  float acc[8] = {0.f,0.f,0.f,0.f,0.f,0.f,0.f,0.f};
  for (int d = lane; d < D_MODEL; d += 64) {
    float xv = x[(size_t)n * D_MODEL + d];
    const float4* g = (const float4*)&gw[d * 8];
    float4 g0 = g[0], g1 = g[1];
    acc[0] += xv * g0.x; acc[1] += xv * g0.y; acc[2] += xv * g0.z; acc[3] += xv * g0.w;
    acc[4] += xv * g1.x; acc[5] += xv * g1.y; acc[6] += xv * g1.z; acc[7] += xv * g1.w;
  }
  for (int off = 32; off; off >>= 1)
    #pragma unroll
    for (int e = 0; e < 8; ++e) acc[e] += __shfl_xor(acc[e], off, 64);
  if (lane == 0) {
    float l[8], p[8];
    float m = -1e30f;
    for (int e = 0; e < 8; ++e) { l[e] = acc[e] + gb[e]; m = fmaxf(m, l[e]); }
    float s = 0.f;
    for (int e = 0; e < 8; ++e) { p[e] = expf(l[e] - m); s += p[e]; }
    float inv = 1.f / s;
    for (int e = 0; e < 8; ++e) p[e] *= inv;
    int i0 = 0;
    for (int e = 1; e < 8; ++e) if (p[e] > p[i0]) i0 = e;          // ties -> lowest idx
    int i1 = (i0 == 0) ? 1 : 0;
    for (int e = 0; e < 8; ++e) if (e != i0 && p[e] > p[i1]) i1 = e;
    tok_idx[2 * n]     = i0;  tok_idx[2 * n + 1] = i1;
    tok_w[2 * n]       = p[i0]; tok_w[2 * n + 1] = p[i1];
    atomicAdd(&counts[i0], 1);
    atomicAdd(&counts[i1], 1);
  }
}

// ---------------- offsets (256-aligned) + load-balancing loss ----------------
__global__ void finalize_routing(const int* __restrict__ counts,
                                 int* __restrict__ offsets,
                                 float* __restrict__ out_loss)
{
  int off = 0;
  for (int e = 0; e < 8; ++e) {
    offsets[e] = off;
    off += ((counts[e] + 255) >> 8) << 8;   // 256-align each expert segment
  }
  offsets[8] = off;
  float loss = 0.f;
  for (int e = 0; e < 8; ++e) {
    float f = (float)counts[e] * (1.f / (float)NASSIGN);
    loss += f * f;
  }
  *out_loss = loss;
}

// ---------------- scatter tokens to expert segments ----------------
__global__ __launch_bounds__(256) void scatter_kernel(
    const int* __restrict__ tok_idx, const float* __restrict__ tok_w,
    const int* __restrict__ offsets, int* __restrict__ cursors,
    int* __restrict__ assign_token, float* __restrict__ assign_w,
    int* __restrict__ tok_pos)
{
  const int n = blockIdx.x * 256 + threadIdx.x;
  #pragma unroll
  for (int k = 0; k < 2; ++k) {
    int e = tok_idx[n * 2 + k];
    int pos = offsets[e] + atomicAdd(&cursors[e], 1);
    assign_token[pos] = n;
    assign_w[pos] = tok_w[n * 2 + k];
    tok_pos[n * 2 + k] = pos;
  }
}

// ---------------- x fp32 -> bf16 ----------------
__global__ __launch_bounds__(256) void convert_x_kernel(
    const float* __restrict__ x, u16* __restrict__ xb)
{
  size_t i = ((size_t)blockIdx.x * 256 + threadIdx.x) * 4;
  float4 v = *(const float4*)&x[i];
  unsigned lo = (unsigned)f2bf(v.x) | ((unsigned)f2bf(v.y) << 16);
  unsigned hi = (unsigned)f2bf(v.z) | ((unsigned)f2bf(v.w) << 16);
  uint2 o; o.x = lo; o.y = hi;
  *(uint2*)&xb[i] = o;
}

// ---------------- transpose+convert: in[e][R][C] fp32 -> out[e][C][R] bf16 ----------------
__global__ __launch_bounds__(256) void transpose_cvt_kernel(
    const float* __restrict__ in, u16* __restrict__ out, int R, int C)
{
  const int e = blockIdx.z;
  const int c0 = blockIdx.x * 32, r0 = blockIdx.y * 32;
  __shared__ float tile[32][33];
  const int tx = threadIdx.x & 31, ty = threadIdx.x >> 5;
  const float* ip = in + (size_t)e * R * C;
  u16* op = out + (size_t)e * R * C;
  #pragma unroll
  for (int i = 0; i < 4; ++i)
    tile[ty + i * 8][tx] = ip[(size_t)(r0 + ty + i * 8) * C + c0 + tx];
  __syncthreads();
  #pragma unroll
  for (int i = 0; i < 4; ++i)
    op[(size_t)(c0 + ty + i * 8) * R + r0 + tx] = f2bf(tile[tx][ty + i * 8]);
}

// ================== m201-cadence 4-phase GEMM core (both GEMMs) ==================
// BM=BN=256, BK=64. 512 threads = 8 waves (2M x 4N), wave-tile 128x64, acc[8][4].
// LDS 128KB: per operand 2dbuf x 2khalf regions of [256 rows][32 k] bf16.
// Phase = { ds_read frags (PRE-barrier); stage; BARRIER; setprio+16 MFMA; BARRIER }.
// ONE counted vmcnt(4) per K-tile at P3's pre-MFMA barrier (m201: never 0 mid-loop).
// Safety: data read in tile t was vmcnt-confirmed + barrier'd at tile t-1's P3.

// ---------------- GEMM1: h = relu(X_gathered @ w1[e] + b1[e]) ----------------
__global__ __launch_bounds__(512, 2) void gemm1_kernel(
    const u16* __restrict__ xb, const u16* __restrict__ w1t,
    const float* __restrict__ b1, const int* __restrict__ assign_token,
    const int* __restrict__ offsets, u16* __restrict__ hbuf)
{
  const int rtl = (blockIdx.x & 7) * 9 + (blockIdx.x >> 3);   // XCD-bijective (72=8*9)
  const int ct = blockIdx.y;                                   // 0..15
  if (rtl * 256 >= offsets[8]) return;
  int e = 0;
  while (offsets[e + 1] <= rtl * 256) ++e;

  __shared__ __align__(16) u16 smem[65536];   // 128 KB

  const int tid = threadIdx.x;
  const int wave = tid >> 6, lane = tid & 63;
  const int wm = wave >> 2, wn = wave & 3;

  // staging: chunk c -> row=c>>2, slot=c&3; src slot = slot^((row>>1)&3)
  const int r0 = tid >> 2, s0 = (tid & 3) ^ ((r0 >> 1) & 3);
  const int r1 = r0 + 128, s1 = (tid & 3) ^ ((r1 >> 1) & 3);
  const long aS0 = (long)assign_token[rtl * 256 + r0] * D_MODEL + s0 * 8;
  const long aS1 = (long)assign_token[rtl * 256 + r1] * D_MODEL + s1 * 8;
  const long bS0 = ((long)e * D_HIDDEN + ct * 256 + r0) * D_MODEL + s0 * 8;
  const long bS1 = ((long)e * D_HIDDEN + ct * 256 + r1) * D_MODEL + s1 * 8;

  f32x4 acc[8][4];
  #pragma unroll
  for (int i = 0; i < 8; ++i)
    #pragma unroll
    for (int j = 0; j < 4; ++j) acc[i][j] = (f32x4){0.f, 0.f, 0.f, 0.f};

  int aoff[8], boff[4];
  #pragma unroll
  for (int f = 0; f < 8; ++f) {
    int row = wm * 128 + f * 16 + (lane & 15);
    aoff[f] = row * 32 + (((lane >> 4) ^ ((row >> 1) & 3)) * 8);
  }
  #pragma unroll
  for (int f = 0; f < 4; ++f) {
    int col = wn * 64 + f * 16 + (lane & 15);
    boff[f] = 32768 + col * 32 + (((lane >> 4) ^ ((col >> 1) & 3)) * 8);
  }

  #define STG1(d, h, koff) do { \
    u16* A_ = &smem[((d) * 2 + (h)) * 8192 + wave * 512]; \
    u16* B_ = &smem[32768 + ((d) * 2 + (h)) * 8192 + wave * 512]; \
    async16(xb  + aS0 + (koff), A_); \
    async16(xb  + aS1 + (koff), A_ + 4096); \
    async16(w1t + bS0 + (koff), B_); \
    async16(w1t + bS1 + (koff), B_ + 4096); \
  } while (0)

  const int NT = D_MODEL / 64;   // 16
  STG1(0, 0, 0);       // klo(0)
  STG1(0, 1, 32);      // khi(0)
  STG1(1, 0, 64);      // klo(1)
  WAIT4_BARRIER();     // klo0,khi0 landed (all waves); klo1 in flight

  for (int t = 0; t < NT; ++t) {
    const int d = t & 1;
    const int reg0 = d * 16384, reg1 = d * 16384 + 8192;
    bf16x8 a[8], b0, b1r, b2, b3;
    // ---- P0: kk=0, cols 0..31  (reads pre-barrier; stage khi(t+1))
    #pragma unroll
    for (int f = 0; f < 8; ++f) a[f] = *(const bf16x8*)&smem[reg0 + aoff[f]];
    b0  = *(const bf16x8*)&smem[reg0 + boff[0]];
    b1r = *(const bf16x8*)&smem[reg0 + boff[1]];
    if (t + 1 < NT) STG1(d ^ 1, 1, (t + 1) * 64 + 32);
    BARRIER();
    __builtin_amdgcn_s_setprio(1);
    #pragma unroll
    for (int f = 0; f < 8; ++f) {
      acc[f][0] = MFMA(a[f], b0, acc[f][0]);
      acc[f][1] = MFMA(a[f], b1r, acc[f][1]);
    }
    __builtin_amdgcn_s_setprio(0);
    BARRIER();
    // ---- P1: kk=0, cols 32..63
    b2 = *(const bf16x8*)&smem[reg0 + boff[2]];
    b3 = *(const bf16x8*)&smem[reg0 + boff[3]];
    BARRIER();
    __builtin_amdgcn_s_setprio(1);
    #pragma unroll
    for (int f = 0; f < 8; ++f) {
      acc[f][2] = MFMA(a[f], b2, acc[f][2]);
      acc[f][3] = MFMA(a[f], b3, acc[f][3]);
    }
    __builtin_amdgcn_s_setprio(0);
    BARRIER();
    // ---- P2: kk=1, cols 0..31  (stage klo(t+2))
    #pragma unroll
    for (int f = 0; f < 8; ++f) a[f] = *(const bf16x8*)&smem[reg1 + aoff[f]];
    b0  = *(const bf16x8*)&smem[reg1 + boff[0]];
    b1r = *(const bf16x8*)&smem[reg1 + boff[1]];
    if (t + 2 < NT) STG1(d, 0, (t + 2) * 64);
    BARRIER();
    __builtin_amdgcn_s_setprio(1);
    #pragma unroll
    for (int f = 0; f < 8; ++f) {
      acc[f][0] = MFMA(a[f], b0, acc[f][0]);
      acc[f][1] = MFMA(a[f], b1r, acc[f][1]);
    }
    __builtin_amdgcn_s_setprio(0);
    BARRIER();
    // ---- P3: kk=1, cols 32..63  (the K-tile's single counted vmcnt wait)
    b2 = *(const bf16x8*)&smem[reg1 + boff[2]];
    b3 = *(const bf16x8*)&smem[reg1 + boff[3]];
    if (t < NT - 2) WAIT4_BARRIER();   // klo(t+1),khi(t+1) landed; klo(t+2) in flight
    else            WAIT0_BARRIER();   // tail: drain everything
    __builtin_amdgcn_s_setprio(1);
    #pragma unroll
    for (int f = 0; f < 8; ++f) {
      acc[f][2] = MFMA(a[f], b2, acc[f][2]);
      acc[f][3] = MFMA(a[f], b3, acc[f][3]);
    }
    __builtin_amdgcn_s_setprio(0);
    BARRIER();
  }
  #undef STG1

  float bias[4];
  #pragma unroll
  for (int j = 0; j < 4; ++j)
    bias[j] = b1[(size_t)e * D_HIDDEN + ct * 256 + wn * 64 + j * 16 + (lane & 15)];

  __syncthreads();
  // Hs overlay: 256x256 bf16 = 128 KB = exactly smem
  u16* Hs = smem;
  #pragma unroll
  for (int i = 0; i < 8; ++i)
    #pragma unroll
    for (int j = 0; j < 4; ++j)
      #pragma unroll
      for (int r = 0; r < 4; ++r) {
        int rl = wm * 128 + i * 16 + ((lane >> 4) * 4) + r;
        int cl = wn * 64 + j * 16 + (lane & 15);
        Hs[rl * 256 + cl] = f2bf(fmaxf(acc[i][j][r] + bias[j], 0.f));
      }
  __syncthreads();
  // 256 rows x 32 chunks of 16B
  #pragma unroll
  for (int it = 0; it < 16; ++it) {
    int cc = tid + it * 512;
    int row = cc >> 5, cs = cc & 31;
    *(uint4*)&hbuf[((size_t)(rtl * 256 + row)) * D_HIDDEN + ct * 256 + cs * 8] =
        *(const uint4*)&Hs[row * 256 + cs * 8];
  }
}

// ---------------- GEMM2 (split-K=2): dst += w * (h @ w2[e] [+ b2 at sk0]) ----------------
template <bool EO>
__global__ __launch_bounds__(512, 2) void gemm2_kernel(
    const u16* __restrict__ hbuf, const u16* __restrict__ w2t,
    const float* __restrict__ b2, const int* __restrict__ assign_token,
    const float* __restrict__ assign_w, const int* __restrict__ offsets,
    float* __restrict__ dst)   // EO ? eo buffer (by pos) : out (by token)
{
  const int rtl = (blockIdx.x & 7) * 9 + (blockIdx.x >> 3);
  const int ct = blockIdx.y;                 // 0..3
  const int sk = blockIdx.z;                 // 0..1
  const long skb = (long)sk * 2048;
  if (rtl * 256 >= offsets[8]) return;
  int e = 0;
  while (offsets[e + 1] <= rtl * 256) ++e;

  __shared__ __align__(16) u16 smem[65536];

  const int tid = threadIdx.x;
  const int wave = tid >> 6, lane = tid & 63;
  const int wm = wave >> 2, wn = wave & 3;

  const int r0 = tid >> 2, s0 = (tid & 3) ^ ((r0 >> 1) & 3);
  const int r1 = r0 + 128, s1 = (tid & 3) ^ ((r1 >> 1) & 3);
  const long aS0 = ((long)(rtl * 256 + r0)) * D_HIDDEN + s0 * 8;
  const long aS1 = ((long)(rtl * 256 + r1)) * D_HIDDEN + s1 * 8;
  const long bS0 = ((long)e * D_MODEL + ct * 256 + r0) * D_HIDDEN + s0 * 8;
  const long bS1 = ((long)e * D_MODEL + ct * 256 + r1) * D_HIDDEN + s1 * 8;

  f32x4 acc[8][4];
  #pragma unroll
  for (int i = 0; i < 8; ++i)
    #pragma unroll
    for (int j = 0; j < 4; ++j) acc[i][j] = (f32x4){0.f, 0.f, 0.f, 0.f};

  int aoff[8], boff[4];
  #pragma unroll
  for (int f = 0; f < 8; ++f) {
    int row = wm * 128 + f * 16 + (lane & 15);
    aoff[f] = row * 32 + (((lane >> 4) ^ ((row >> 1) & 3)) * 8);
  }
  #pragma unroll
  for (int f = 0; f < 4; ++f) {
    int col = wn * 64 + f * 16 + (lane & 15);
    boff[f] = 32768 + col * 32 + (((lane >> 4) ^ ((col >> 1) & 3)) * 8);
  }

  #define STG2(d, h, koff) do { \
    u16* A_ = &smem[((d) * 2 + (h)) * 8192 + wave * 512]; \
    u16* B_ = &smem[32768 + ((d) * 2 + (h)) * 8192 + wave * 512]; \
    async16(hbuf + aS0 + (koff), A_); \
    async16(hbuf + aS1 + (koff), A_ + 4096); \
    async16(w2t + bS0 + (koff), B_); \
    async16(w2t + bS1 + (koff), B_ + 4096); \
  } while (0)

  const int NT = 2048 / 64;   // 32
  STG2(0, 0, skb);
  STG2(0, 1, skb + 32);
  STG2(1, 0, skb + 64);
  WAIT4_BARRIER();

  for (int t = 0; t < NT; ++t) {
    const int d = t & 1;
    const int reg0 = d * 16384, reg1 = d * 16384 + 8192;
    bf16x8 a[8], b0, b1r, b2, b3;
    // ---- P0
    #pragma unroll
    for (int f = 0; f < 8; ++f) a[f] = *(const bf16x8*)&smem[reg0 + aoff[f]];
    b0  = *(const bf16x8*)&smem[reg0 + boff[0]];
    b1r = *(const bf16x8*)&smem[reg0 + boff[1]];
    if (t + 1 < NT) STG2(d ^ 1, 1, skb + (t + 1) * 64 + 32);
    BARRIER();
    __builtin_amdgcn_s_setprio(1);
    #pragma unroll
    for (int f = 0; f < 8; ++f) {
      acc[f][0] = MFMA(a[f], b0, acc[f][0]);
      acc[f][1] = MFMA(a[f], b1r, acc[f][1]);
    }
    __builtin_amdgcn_s_setprio(0);
    BARRIER();
    // ---- P1
    b2 = *(const bf16x8*)&smem[reg0 + boff[2]];
    b3 = *(const bf16x8*)&smem[reg0 + boff[3]];
    BARRIER();
    __builtin_amdgcn_s_setprio(1);
    #pragma unroll
    for (int f = 0; f < 8; ++f) {
      acc[f][2] = MFMA(a[f], b2, acc[f][2]);
      acc[f][3] = MFMA(a[f], b3, acc[f][3]);
    }
    __builtin_amdgcn_s_setprio(0);
    BARRIER();
    // ---- P2
    #pragma unroll
    for (int f = 0; f < 8; ++f) a[f] = *(const bf16x8*)&smem[reg1 + aoff[f]];
    b0  = *(const bf16x8*)&smem[reg1 + boff[0]];
    b1r = *(const bf16x8*)&smem[reg1 + boff[1]];
    if (t + 2 < NT) STG2(d, 0, skb + (t + 2) * 64);
    BARRIER();
    __builtin_amdgcn_s_setprio(1);
    #pragma unroll
    for (int f = 0; f < 8; ++f) {
      acc[f][0] = MFMA(a[f], b0, acc[f][0]);
      acc[f][1] = MFMA(a[f], b1r, acc[f][1]);
    }
    __builtin_amdgcn_s_setprio(0);
    BARRIER();
    // ---- P3 (counted vmcnt once per K-tile)
    b2 = *(const bf16x8*)&smem[reg1 + boff[2]];
    b3 = *(const bf16x8*)&smem[reg1 + boff[3]];
    if (t < NT - 2) WAIT4_BARRIER();
    else            WAIT0_BARRIER();
    __builtin_amdgcn_s_setprio(1);
    #pragma unroll
    for (int f = 0; f < 8; ++f) {
      acc[f][2] = MFMA(a[f], b2, acc[f][2]);
      acc[f][3] = MFMA(a[f], b3, acc[f][3]);
    }
    __builtin_amdgcn_s_setprio(0);
    BARRIER();
  }
  #undef STG2

  float bias[4];
  #pragma unroll
  for (int j = 0; j < 4; ++j)
    bias[j] = (sk == 0) ? b2[(size_t)e * D_MODEL + ct * 256 + wn * 64 + j * 16 + (lane & 15)] : 0.f;

  __syncthreads();
  float* wsm = (float*)smem;
  int* tsm = (int*)&smem[1024];
  if (tid < 256) {
    wsm[tid] = assign_w[rtl * 256 + tid];
    tsm[tid] = assign_token[rtl * 256 + tid];
  }
  __syncthreads();

  #pragma unroll
  for (int i = 0; i < 8; ++i)
    #pragma unroll
    for (int r = 0; r < 4; ++r) {
      int rl = wm * 128 + i * 16 + ((lane >> 4) * 4) + r;
      float wgt = wsm[rl];
      if (EO) {
        size_t row = (size_t)(rtl * 256 + rl);
        #pragma unroll
        for (int j = 0; j < 4; ++j) {
          float v = (acc[i][j][r] + bias[j]) * wgt;
          atomicAdd(&dst[row * D_MODEL + ct * 256 + wn * 64 + j * 16 + (lane & 15)], v);
        }
      } else {
        int tok = tsm[rl];
        #pragma unroll
        for (int j = 0; j < 4; ++j) {
          float v = (acc[i][j][r] + bias[j]) * wgt;
          atomicAdd(&dst[(size_t)tok * D_MODEL + ct * 256 + wn * 64 + j * 16 + (lane & 15)], v);
        }
      }
    }
}

// ---------------- combine: out[n] = eo[pos0] + eo[pos1] ----------------
__global__ __launch_bounds__(256) void combine_kernel(
    const float* __restrict__ eo, const int* __restrict__ tok_pos,
    float* __restrict__ out)
{
  int idx = blockIdx.x * 256 + threadIdx.x;   // one float4 per thread
  int n = idx >> 8;                           // 256 float4 per token
  int c = (idx & 255) * 4;
  int p0 = tok_pos[2 * n], p1 = tok_pos[2 * n + 1];
  float4 a = *(const float4*)&eo[(size_t)p0 * D_MODEL + c];
  float4 b = *(const float4*)&eo[(size_t)p1 * D_MODEL + c];
  float4 o; o.x = a.x + b.x; o.y = a.y + b.y; o.z = a.z + b.z; o.w = a.w + b.w;
  *(float4*)&out[(size_t)n * D_MODEL + c] = o;
}

// ---------------- fallback (tiny ws): naive fp32 per-assignment ----------------
__global__ __launch_bounds__(256) void moe_fallback_kernel(
    const float* __restrict__ x, const float* __restrict__ w1,
    const float* __restrict__ b1, const float* __restrict__ w2,
    const float* __restrict__ b2, const int* __restrict__ tok_idx,
    const float* __restrict__ tok_w, float* __restrict__ out)
{
  const int a = blockIdx.x;
  const int n = a >> 1, slot = a & 1;
  const int e = tok_idx[n * 2 + slot];
  const float wgt = tok_w[n * 2 + slot];
  __shared__ float xs[D_MODEL];
  __shared__ float hs[D_HIDDEN];
  const int tid = threadIdx.x;
  for (int d = tid; d < D_MODEL; d += 256) xs[d] = x[(size_t)n * D_MODEL + d];
  __syncthreads();
  for (int h = tid; h < D_HIDDEN; h += 256) {
    float acc = b1[(size_t)e * D_HIDDEN + h];
    for (int d = 0; d < D_MODEL; ++d)
      acc += xs[d] * w1[((size_t)e * D_MODEL + d) * D_HIDDEN + h];
    hs[h] = fmaxf(acc, 0.f);
  }
  __syncthreads();
  for (int d = tid; d < D_MODEL; d += 256) {
    float acc = b2[(size_t)e * D_MODEL + d];
    for (int h = 0; h < D_HIDDEN; ++h)
      acc += hs[h] * w2[((size_t)e * D_HIDDEN + h) * D_MODEL + d];
    atomicAdd(&out[(size_t)n * D_MODEL + d], wgt * acc);
  }
}

extern "C" void kernel_launch(void* const* d_in, const int* in_sizes, int n_in,
                              void* d_out, int out_size, void* d_ws, size_t ws_size,
                              hipStream_t stream) {
  const float* x      = (const float*)d_in[0];
  const float* gate_w = (const float*)d_in[1];
  const float* gate_b = (const float*)d_in[2];
  const float* w1     = (const float*)d_in[3];
  const float* b1     = (const float*)d_in[4];
  const float* w2     = (const float*)d_in[5];
  const float* b2     = (const float*)d_in[6];
  float* out = (float*)d_out;

  char* ws = (char*)d_ws;
  int*   counts       = (int*)(ws + 0);
  int*   cursors      = (int*)(ws + 32);
  int*   offsets      = (int*)(ws + 64);
  int*   tok_idx      = (int*)(ws + 256);       // 64 KB
  float* tok_w        = (float*)(ws + 65792);   // 64 KB
  int*   tok_pos      = (int*)(ws + 131328);    // 64 KB
  int*   assign_token = (int*)(ws + 196864);    // 72 KB (PADCAP ints)
  float* assign_w     = (float*)(ws + 270592);  // 72 KB
  const size_t X0 = 344320;
  // gemm1 live:  hbuf [X0, X0+144M) | xb [X0+144M, +16M) | w1t [X0+160M, +64M)
  // gemm2 live:  hbuf | w2t (aliases xb+w1t head) | eo [X0+208M, +72M) (aliases w1t tail)
  u16*   hbuf = (u16*)(ws + X0);
  u16*   xb   = (u16*)(ws + X0 + 150994944ull);
  u16*   w1t  = (u16*)(ws + X0 + 150994944ull + 16777216ull);
  u16*   w2t  = (u16*)(ws + X0 + 150994944ull);                 // 64 MB, dead xb+w1t
  float* eo   = (float*)(ws + X0 + 150994944ull + 67108864ull); // [PADCAP][1024] fp32
  const size_t REQ_FAST = X0 + 150994944ull + 16777216ull + 67108864ull; // ~224.8 MiB
  const size_t REQ_EO   = X0 + 150994944ull + 67108864ull + 75497472ull; // ~280.3 MiB

  const bool fast = (ws_size >= REQ_FAST);
  const bool eoPath = fast && (ws_size >= REQ_EO);

  // zero routing scratch (incl. pad entries of assign_* -> token 0, weight 0)
  hipMemsetAsync(ws, 0, X0, stream);
  if (!eoPath) {
    hipMemsetAsync(d_out, 0, (size_t)out_size * sizeof(float), stream);
  }

  gating_kernel<<<N_TOKENS / 4, 256, 0, stream>>>(x, gate_w, gate_b, counts, tok_idx, tok_w);
  finalize_routing<<<1, 1, 0, stream>>>(counts, offsets, out + (out_size - 1));

  if (fast) {
    scatter_kernel<<<N_TOKENS / 256, 256, 0, stream>>>(tok_idx, tok_w, offsets, cursors,
                                                       assign_token, assign_w, tok_pos);
    convert_x_kernel<<<(N_TOKENS * D_MODEL) / 1024, 256, 0, stream>>>(x, xb);
    transpose_cvt_kernel<<<dim3(D_HIDDEN / 32, D_MODEL / 32, N_EXPERTS), 256, 0, stream>>>(
        w1, w1t, D_MODEL, D_HIDDEN);
    gemm1_kernel<<<dim3(RT_TILES, D_HIDDEN / 256), 512, 0, stream>>>(
        xb, w1t, b1, assign_token, offsets, hbuf);
    transpose_cvt_kernel<<<dim3(D_MODEL / 32, D_HIDDEN / 32, N_EXPERTS), 256, 0, stream>>>(
        w2, w2t, D_HIDDEN, D_MODEL);
    if (eoPath) {
      // CRITICAL ORDER: eo overlaps w1t's tail; zero it only AFTER the w1t
      // transpose (last overlapping writer) is enqueued. (R7/R8 bug.)
      hipMemsetAsync(eo, 0, 75497472ull, stream);   // split-K accumulates atomically
      gemm2_kernel<true><<<dim3(RT_TILES, D_MODEL / 256, 2), 512, 0, stream>>>(
          hbuf, w2t, b2, assign_token, assign_w, offsets, eo);
      combine_kernel<<<(N_TOKENS * D_MODEL) / 1024, 256, 0, stream>>>(eo, tok_pos, out);
    } else {
      gemm2_kernel<false><<<dim3(RT_TILES, D_MODEL / 256, 2), 512, 0, stream>>>(
          hbuf, w2t, b2, assign_token, assign_w, offsets, out);
    }
  } else {
    moe_fallback_kernel<<<NASSIGN, 256, 0, stream>>>(x, w1, b1, w2, b2, tok_idx, tok_w, out);
  }
}

// Round 13
// 749.333 us; speedup vs baseline: 1.1834x; 1.1298x over previous
//
#include <hip/hip_runtime.h>

#define D_MODEL   1024
#define D_HIDDEN  4096
#define N_EXPERTS 8
#define N_TOKENS  8192
#define NASSIGN   (N_TOKENS * 2)               // 16384
#define PADCAP    (NASSIGN + N_EXPERTS * 128)  // 17408
#define ROWT      (PADCAP / 128)               // 136 = 8*17

typedef unsigned short u16;
typedef __bf16 bf16x8 __attribute__((ext_vector_type(8)));
typedef float  f32x4  __attribute__((ext_vector_type(4)));

__device__ __forceinline__ u16 f2bf(float f) {
  union { float f; unsigned u; } c; c.f = f;
  unsigned u = c.u;
  u = (u + 0x7fffu + ((u >> 16) & 1u)) >> 16;   // RNE
  return (u16)u;
}

__device__ __forceinline__ void async16(const void* g, void* l) {
  __builtin_amdgcn_global_load_lds(
      (const __attribute__((address_space(1))) unsigned int*)g,
      (__attribute__((address_space(3))) unsigned int*)l, 16, 0, 0);
}

// ---------------- gating (vectorized, fused x->bf16): 4 tokens/block ----------------
// Each lane covers float4 indices {lane, lane+64, lane+128, lane+192} -> full 1024 row.
// (R12 bug: one float4/lane covered only 1/4 of the row; xb was 3/4 poison.)
__global__ __launch_bounds__(256) void gating_kernel(
    const float* __restrict__ x, const float* __restrict__ gw,
    const float* __restrict__ gb, int* __restrict__ counts,
    int* __restrict__ tok_idx, float* __restrict__ tok_w,
    u16* __restrict__ xb)
{
  const int n = blockIdx.x * 4 + (threadIdx.x >> 6);
  const int lane = threadIdx.x & 63;
  const float4* x4 = (const float4*)x;
  const float4* gw4 = (const float4*)gw;

  float acc[8] = {0.f,0.f,0.f,0.f,0.f,0.f,0.f,0.f};
  #pragma unroll
  for (int cch = 0; cch < 4; ++cch) {
    const int f4i = cch * 64 + lane;                 // float4 index in row, 0..255
    float4 xv = x4[(size_t)n * 256 + f4i];

    uint2 o;
    o.x = (unsigned)f2bf(xv.x) | ((unsigned)f2bf(xv.y) << 16);
    o.y = (unsigned)f2bf(xv.z) | ((unsigned)f2bf(xv.w) << 16);
    *(uint2*)&xb[(size_t)n * D_MODEL + f4i * 4] = o;

    float xr[4] = {xv.x, xv.y, xv.z, xv.w};
    #pragma unroll
    for (int r = 0; r < 4; ++r) {
      int row = f4i * 4 + r;
      float4 g0 = gw4[row * 2], g1 = gw4[row * 2 + 1];   // gw is 32KB, L1/L2-hot
      acc[0] += xr[r] * g0.x; acc[1] += xr[r] * g0.y;
      acc[2] += xr[r] * g0.z; acc[3] += xr[r] * g0.w;
      acc[4] += xr[r] * g1.x; acc[5] += xr[r] * g1.y;
      acc[6] += xr[r] * g1.z; acc[7] += xr[r] * g1.w;
    }
  }
  for (int off = 32; off; off >>= 1)
    #pragma unroll
    for (int e = 0; e < 8; ++e) acc[e] += __shfl_xor(acc[e], off, 64);
  if (lane == 0) {
    float l[8], p[8];
    float m = -1e30f;
    for (int e = 0; e < 8; ++e) { l[e] = acc[e] + gb[e]; m = fmaxf(m, l[e]); }
    float s = 0.f;
    for (int e = 0; e < 8; ++e) { p[e] = expf(l[e] - m); s += p[e]; }
    float inv = 1.f / s;
    for (int e = 0; e < 8; ++e) p[e] *= inv;
    int i0 = 0;
    for (int e = 1; e < 8; ++e) if (p[e] > p[i0]) i0 = e;          // ties -> lowest idx
    int i1 = (i0 == 0) ? 1 : 0;
    for (int e = 0; e < 8; ++e) if (e != i0 && p[e] > p[i1]) i1 = e;
    tok_idx[2 * n]     = i0;  tok_idx[2 * n + 1] = i1;
    tok_w[2 * n]       = p[i0]; tok_w[2 * n + 1] = p[i1];
    atomicAdd(&counts[i0], 1);
    atomicAdd(&counts[i1], 1);
  }
}

// ---------------- offsets + load-balancing loss ----------------
__global__ void finalize_routing(const int* __restrict__ counts,
                                 int* __restrict__ offsets,
                                 float* __restrict__ out_loss)
{
  int off = 0;
  for (int e = 0; e < 8; ++e) {
    offsets[e] = off;
    off += ((counts[e] + 127) >> 7) << 7;   // 128-align each expert segment
  }
  offsets[8] = off;
  float loss = 0.f;
  for (int e = 0; e < 8; ++e) {
    float f = (float)counts[e] * (1.f / (float)NASSIGN);
    loss += f * f;
  }
  *out_loss = loss;
}

// ---------------- scatter tokens to expert segments ----------------
__global__ __launch_bounds__(256) void scatter_kernel(
    const int* __restrict__ tok_idx, const float* __restrict__ tok_w,
    const int* __restrict__ offsets, int* __restrict__ cursors,
    int* __restrict__ assign_token, float* __restrict__ assign_w,
    int* __restrict__ tok_pos)
{
  const int n = blockIdx.x * 256 + threadIdx.x;
  #pragma unroll
  for (int k = 0; k < 2; ++k) {
    int e = tok_idx[n * 2 + k];
    int pos = offsets[e] + atomicAdd(&cursors[e], 1);
    assign_token[pos] = n;
    assign_w[pos] = tok_w[n * 2 + k];
    tok_pos[n * 2 + k] = pos;
  }
}

// ---------------- transpose+convert (vectorized): in[e][R][C] f32 -> out[e][C][R] bf16 ----
__global__ __launch_bounds__(256) void transpose_cvt_kernel(
    const float* __restrict__ in, u16* __restrict__ out, int R, int C)
{
  const int e = blockIdx.z;
  const int c0 = blockIdx.x * 64, r0 = blockIdx.y * 64;
  __shared__ float tile[64][65];
  const int tx = threadIdx.x & 15;        // 16 x float4 = 64 cols
  const int ty = threadIdx.x >> 4;        // 16 rows/pass
  const float* ip = in + (size_t)e * R * C;
  u16* op = out + (size_t)e * R * C;
  #pragma unroll
  for (int i = 0; i < 4; ++i) {
    int r = ty + i * 16;
    float4 v = *(const float4*)&ip[(size_t)(r0 + r) * C + c0 + tx * 4];
    tile[r][tx * 4 + 0] = v.x; tile[r][tx * 4 + 1] = v.y;
    tile[r][tx * 4 + 2] = v.z; tile[r][tx * 4 + 3] = v.w;
  }
  __syncthreads();
  const int c = threadIdx.x >> 2, seg = threadIdx.x & 3;   // out-row c, 32B segment
  u16 buf[16];
  #pragma unroll
  for (int k = 0; k < 16; ++k) buf[k] = f2bf(tile[seg * 16 + k][c]);
  *(uint4*)&op[(size_t)(c0 + c) * R + r0 + seg * 16]     = *(const uint4*)&buf[0];
  *(uint4*)&op[(size_t)(c0 + c) * R + r0 + seg * 16 + 8] = *(const uint4*)&buf[8];
}

// ================== GEMM core (R5 config, best measured) ==================
// BM=128, BN=256, BK=32. 256 threads = 4 waves, wave-tile 64x128 (acc 4x8).
// 3 cyclic LDS buffers (72KB -> 2 blocks/CU), counted vmcnt(6), raw s_barrier.
// XCD-bijective rt swizzle: 136 = 8*17.

// ---------------- GEMM1: h = relu(X_gathered @ w1[e] + b1[e]) ----------------
__global__ __launch_bounds__(256, 2) void gemm1_kernel(
    const u16* __restrict__ xb, const u16* __restrict__ w1t,
    const float* __restrict__ b1, const int* __restrict__ assign_token,
    const int* __restrict__ offsets, u16* __restrict__ hbuf)
{
  const int rt = (blockIdx.x & 7) * 17 + (blockIdx.x >> 3);   // XCD-bijective
  const int ct = blockIdx.y;   // ct in [0,16)
  if (rt * 128 >= offsets[8]) return;
  int e = 0;
  while (offsets[e + 1] <= rt * 128) ++e;

  // A bufs: 3 x 4096 u16 (128x32, 8KB); B bufs: 3 x 8192 u16 (256x32, 16KB). 72KB.
  __shared__ __align__(16) u16 smem[36864];
  u16* Asm = smem;            // [0, 12288)
  u16* Bsm = smem + 12288;    // [12288, 36864)

  const int tid = threadIdx.x;
  const int wave = tid >> 6, lane = tid & 63;

  const int ra0 = tid >> 2,         sa = tid & 3;
  const int ra1 = (tid + 256) >> 2;
  const int sga0 = sa ^ ((ra0 >> 1) & 3);
  const int sga1 = sa ^ ((ra1 >> 1) & 3);
  const long aBase0 = (long)assign_token[rt * 128 + ra0] * D_MODEL + sga0 * 8;
  const long aBase1 = (long)assign_token[rt * 128 + ra1] * D_MODEL + sga1 * 8;

  long bBase[4];
  #pragma unroll
  for (int k = 0; k < 4; ++k) {
    int c = tid + k * 256;
    int r = c >> 2, s = c & 3;
    int sg = s ^ ((r >> 1) & 3);
    bBase[k] = ((long)e * D_HIDDEN + ct * 256 + r) * D_MODEL + sg * 8;
  }

  const int wr = (wave >> 1) * 64;    // wave row base (0/64)
  const int wc = (wave & 1) * 128;    // wave col base (0/128)
  f32x4 acc[4][8];
  #pragma unroll
  for (int i = 0; i < 4; ++i)
    #pragma unroll
    for (int j = 0; j < 8; ++j) acc[i][j] = (f32x4){0.f, 0.f, 0.f, 0.f};

  int aoff[4], boff[8];
  #pragma unroll
  for (int i = 0; i < 4; ++i) {
    int row = wr + i * 16 + (lane & 15);
    aoff[i] = row * 32 + (((lane >> 4) ^ ((row >> 1) & 3)) * 8);
  }
  #pragma unroll
  for (int j = 0; j < 8; ++j) {
    int col = wc + j * 16 + (lane & 15);
    boff[j] = col * 32 + (((lane >> 4) ^ ((col >> 1) & 3)) * 8);
  }

  #define STAGE1(bi, k0) do { \
    u16* A_ = Asm + (bi) * 4096; \
    u16* B_ = Bsm + (bi) * 8192; \
    async16(xb  + aBase0   + (k0), A_ + wave * 512); \
    async16(xb  + aBase1   + (k0), A_ + 2048 + wave * 512); \
    async16(w1t + bBase[0] + (k0), B_ + wave * 512); \
    async16(w1t + bBase[1] + (k0), B_ + 2048 + wave * 512); \
    async16(w1t + bBase[2] + (k0), B_ + 4096 + wave * 512); \
    async16(w1t + bBase[3] + (k0), B_ + 6144 + wave * 512); \
  } while (0)

  const int NT = D_MODEL / 32;   // 32
  STAGE1(0, 0);
  STAGE1(1, 32);
  int bi = 0;
  for (int t = 0; t < NT; ++t) {
    if (t < NT - 1) asm volatile("s_waitcnt vmcnt(6)" ::: "memory");
    else            asm volatile("s_waitcnt vmcnt(0)" ::: "memory");
    __builtin_amdgcn_s_barrier();
    const u16* A = Asm + bi * 4096;
    const u16* B = Bsm + bi * 8192;
    bf16x8 a[4], b[8];
    #pragma unroll
    for (int i = 0; i < 4; ++i) a[i] = *(const bf16x8*)&A[aoff[i]];
    #pragma unroll
    for (int j = 0; j < 8; ++j) b[j] = *(const bf16x8*)&B[boff[j]];
    __builtin_amdgcn_s_setprio(1);
    #pragma unroll
    for (int i = 0; i < 4; ++i)
      #pragma unroll
      for (int j = 0; j < 8; ++j)
        acc[i][j] = __builtin_amdgcn_mfma_f32_16x16x32_bf16(a[i], b[j], acc[i][j], 0, 0, 0);
    __builtin_amdgcn_s_setprio(0);
    if (t + 2 < NT) {
      int nb = bi + 2; if (nb >= 3) nb -= 3;
      STAGE1(nb, (t + 2) * 32);
    }
    ++bi; if (bi == 3) bi = 0;
  }
  #undef STAGE1

  float bias[8];
  #pragma unroll
  for (int j = 0; j < 8; ++j)
    bias[j] = b1[(size_t)e * D_HIDDEN + ct * 256 + wc + j * 16 + (lane & 15)];

  __syncthreads();   // all LDS reads of staging bufs done before Hs overlay
  // Hs overlays the staging buffers: 32768 u16 = 128x256 bf16 (fits in 36864).
  u16* Hs = smem;
  #pragma unroll
  for (int i = 0; i < 4; ++i)
    #pragma unroll
    for (int j = 0; j < 8; ++j)
      #pragma unroll
      for (int r = 0; r < 4; ++r) {
        int rl = wr + i * 16 + ((lane >> 4) * 4) + r;
        int cl = wc + j * 16 + (lane & 15);
        Hs[rl * 256 + cl] = f2bf(fmaxf(acc[i][j][r] + bias[j], 0.f));
      }
  __syncthreads();
  // 128 rows x 32 chunks of 16B = 128x256 bf16 tile
  #pragma unroll
  for (int t = 0; t < 16; ++t) {
    int cc = tid + t * 256;
    int row = cc >> 5, cs = cc & 31;
    *(uint4*)&hbuf[((size_t)(rt * 128 + row)) * D_HIDDEN + ct * 256 + cs * 8] =
        *(const uint4*)&Hs[row * 256 + cs * 8];
  }
}

// ---------------- GEMM2: eo[pos] = w * (h @ w2[e] + b2[e])  (or atomic into out) ---------
template <bool EO>
__global__ __launch_bounds__(256, 2) void gemm2_kernel(
    const u16* __restrict__ hbuf, const u16* __restrict__ w2t,
    const float* __restrict__ b2, const int* __restrict__ assign_token,
    const float* __restrict__ assign_w, const int* __restrict__ offsets,
    float* __restrict__ dst)   // EO ? eo buffer : out
{
  const int rt = (blockIdx.x & 7) * 17 + (blockIdx.x >> 3);   // XCD-bijective
  const int ct = blockIdx.y;   // ct in [0,4)
  if (rt * 128 >= offsets[8]) return;
  int e = 0;
  while (offsets[e + 1] <= rt * 128) ++e;

  __shared__ __align__(16) u16 smem[36864];
  u16* Asm = smem;
  u16* Bsm = smem + 12288;
  __shared__ int tokS[128];
  __shared__ float wS[128];

  const int tid = threadIdx.x;
  const int wave = tid >> 6, lane = tid & 63;
  if (tid < 128) {
    tokS[tid] = assign_token[rt * 128 + tid];
    wS[tid] = assign_w[rt * 128 + tid];
  }

  const int ra0 = tid >> 2,         sa = tid & 3;
  const int ra1 = (tid + 256) >> 2;
  const int sga0 = sa ^ ((ra0 >> 1) & 3);
  const int sga1 = sa ^ ((ra1 >> 1) & 3);
  const long aBase0 = ((long)(rt * 128 + ra0)) * D_HIDDEN + sga0 * 8;
  const long aBase1 = ((long)(rt * 128 + ra1)) * D_HIDDEN + sga1 * 8;

  long bBase[4];
  #pragma unroll
  for (int k = 0; k < 4; ++k) {
    int c = tid + k * 256;
    int r = c >> 2, s = c & 3;
    int sg = s ^ ((r >> 1) & 3);
    bBase[k] = ((long)e * D_MODEL + ct * 256 + r) * D_HIDDEN + sg * 8;
  }

  const int wr = (wave >> 1) * 64;
  const int wc = (wave & 1) * 128;
  f32x4 acc[4][8];
  #pragma unroll
  for (int i = 0; i < 4; ++i)
    #pragma unroll
    for (int j = 0; j < 8; ++j) acc[i][j] = (f32x4){0.f, 0.f, 0.f, 0.f};

  int aoff[4], boff[8];
  #pragma unroll
  for (int i = 0; i < 4; ++i) {
    int row = wr + i * 16 + (lane & 15);
    aoff[i] = row * 32 + (((lane >> 4) ^ ((row >> 1) & 3)) * 8);
  }
  #pragma unroll
  for (int j = 0; j < 8; ++j) {
    int col = wc + j * 16 + (lane & 15);
    boff[j] = col * 32 + (((lane >> 4) ^ ((col >> 1) & 3)) * 8);
  }

  #define STAGE2(bi, k0) do { \
    u16* A_ = Asm + (bi) * 4096; \
    u16* B_ = Bsm + (bi) * 8192; \
    async16(hbuf + aBase0   + (k0), A_ + wave * 512); \
    async16(hbuf + aBase1   + (k0), A_ + 2048 + wave * 512); \
    async16(w2t  + bBase[0] + (k0), B_ + wave * 512); \
    async16(w2t  + bBase[1] + (k0), B_ + 2048 + wave * 512); \
    async16(w2t  + bBase[2] + (k0), B_ + 4096 + wave * 512); \
    async16(w2t  + bBase[3] + (k0), B_ + 6144 + wave * 512); \
  } while (0)

  const int NT = D_HIDDEN / 32;   // 128
  STAGE2(0, 0);
  STAGE2(1, 32);
  int bi = 0;
  for (int t = 0; t < NT; ++t) {
    if (t < NT - 1) asm volatile("s_waitcnt vmcnt(6)" ::: "memory");
    else            asm volatile("s_waitcnt vmcnt(0)" ::: "memory");
    __builtin_amdgcn_s_barrier();
    const u16* A = Asm + bi * 4096;
    const u16* B = Bsm + bi * 8192;
    bf16x8 a[4], b[8];
    #pragma unroll
    for (int i = 0; i < 4; ++i) a[i] = *(const bf16x8*)&A[aoff[i]];
    #pragma unroll
    for (int j = 0; j < 8; ++j) b[j] = *(const bf16x8*)&B[boff[j]];
    __builtin_amdgcn_s_setprio(1);
    #pragma unroll
    for (int i = 0; i < 4; ++i)
      #pragma unroll
      for (int j = 0; j < 8; ++j)
        acc[i][j] = __builtin_amdgcn_mfma_f32_16x16x32_bf16(a[i], b[j], acc[i][j], 0, 0, 0);
    __builtin_amdgcn_s_setprio(0);
    if (t + 2 < NT) {
      int nb = bi + 2; if (nb >= 3) nb -= 3;
      STAGE2(nb, (t + 2) * 32);
    }
    ++bi; if (bi == 3) bi = 0;
  }
  #undef STAGE2

  float bias[8];
  #pragma unroll
  for (int j = 0; j < 8; ++j)
    bias[j] = b2[(size_t)e * D_MODEL + ct * 256 + wc + j * 16 + (lane & 15)];

  #pragma unroll
  for (int i = 0; i < 4; ++i)
    #pragma unroll
    for (int r = 0; r < 4; ++r) {
      int rl = wr + i * 16 + ((lane >> 4) * 4) + r;
      float wgt = wS[rl];
      if (EO) {
        size_t row = (size_t)(rt * 128 + rl);
        #pragma unroll
        for (int j = 0; j < 8; ++j) {
          float v = (acc[i][j][r] + bias[j]) * wgt;
          dst[row * D_MODEL + ct * 256 + wc + j * 16 + (lane & 15)] = v;
        }
      } else {
        int tok = tokS[rl];
        #pragma unroll
        for (int j = 0; j < 8; ++j) {
          float v = (acc[i][j][r] + bias[j]) * wgt;
          atomicAdd(&dst[(size_t)tok * D_MODEL + ct * 256 + wc + j * 16 + (lane & 15)], v);
        }
      }
    }
}

// ---------------- combine: out[n] = eo[pos0] + eo[pos1] ----------------
__global__ __launch_bounds__(256) void combine_kernel(
    const float* __restrict__ eo, const int* __restrict__ tok_pos,
    float* __restrict__ out)
{
  int idx = blockIdx.x * 256 + threadIdx.x;   // one float4 per thread
  int n = idx >> 8;                           // 256 float4 per token
  int c = (idx & 255) * 4;
  int p0 = tok_pos[2 * n], p1 = tok_pos[2 * n + 1];
  float4 a = *(const float4*)&eo[(size_t)p0 * D_MODEL + c];
  float4 b = *(const float4*)&eo[(size_t)p1 * D_MODEL + c];
  float4 o; o.x = a.x + b.x; o.y = a.y + b.y; o.z = a.z + b.z; o.w = a.w + b.w;
  *(float4*)&out[(size_t)n * D_MODEL + c] = o;
}

// ---------------- fallback (tiny ws): naive fp32 per-assignment ----------------
__global__ __launch_bounds__(256) void moe_fallback_kernel(
    const float* __restrict__ x, const float* __restrict__ w1,
    const float* __restrict__ b1, const float* __restrict__ w2,
    const float* __restrict__ b2, const int* __restrict__ tok_idx,
    const float* __restrict__ tok_w, float* __restrict__ out)
{
  const int a = blockIdx.x;
  const int n = a >> 1, slot = a & 1;
  const int e = tok_idx[n * 2 + slot];
  const float wgt = tok_w[n * 2 + slot];
  __shared__ float xs[D_MODEL];
  __shared__ float hs[D_HIDDEN];
  const int tid = threadIdx.x;
  for (int d = tid; d < D_MODEL; d += 256) xs[d] = x[(size_t)n * D_MODEL + d];
  __syncthreads();
  for (int h = tid; h < D_HIDDEN; h += 256) {
    float acc = b1[(size_t)e * D_HIDDEN + h];
    for (int d = 0; d < D_MODEL; ++d)
      acc += xs[d] * w1[((size_t)e * D_MODEL + d) * D_HIDDEN + h];
    hs[h] = fmaxf(acc, 0.f);
  }
  __syncthreads();
  for (int d = tid; d < D_MODEL; d += 256) {
    float acc = b2[(size_t)e * D_MODEL + d];
    for (int h = 0; h < D_HIDDEN; ++h)
      acc += hs[h] * w2[((size_t)e * D_HIDDEN + h) * D_MODEL + d];
    atomicAdd(&out[(size_t)n * D_MODEL + d], wgt * acc);
  }
}

extern "C" void kernel_launch(void* const* d_in, const int* in_sizes, int n_in,
                              void* d_out, int out_size, void* d_ws, size_t ws_size,
                              hipStream_t stream) {
  const float* x      = (const float*)d_in[0];
  const float* gate_w = (const float*)d_in[1];
  const float* gate_b = (const float*)d_in[2];
  const float* w1     = (const float*)d_in[3];
  const float* b1     = (const float*)d_in[4];
  const float* w2     = (const float*)d_in[5];
  const float* b2     = (const float*)d_in[6];
  float* out = (float*)d_out;

  char* ws = (char*)d_ws;
  int*   counts       = (int*)(ws + 0);
  int*   cursors      = (int*)(ws + 32);
  int*   offsets      = (int*)(ws + 64);
  int*   tok_idx      = (int*)(ws + 256);       // 64 KB
  float* tok_w        = (float*)(ws + 65792);   // 64 KB
  int*   tok_pos      = (int*)(ws + 131328);    // 64 KB
  int*   assign_token = (int*)(ws + 196864);    // 68 KB
  float* assign_w     = (float*)(ws + 266496);  // 68 KB
  const size_t X0 = 336128;
  u16* xb   = (u16*)(ws + X0);
  u16* w1t  = (u16*)(ws + X0 + 16777216);
  u16* w2t  = (u16*)(ws + X0);                  // aliases xb+w1t (dead after GEMM1)
  u16* hbuf = (u16*)(ws + X0 + 83886080);
  float* eo = (float*)(ws + X0 + 226492416ull); // [PADCAP][1024] fp32 (no w1t overlap)
  const size_t REQ_FAST = X0 + 226492416ull;                 // ~216 MiB
  const size_t REQ_EO   = REQ_FAST + 71303168ull;            // ~284 MiB

  const bool fast = (ws_size >= REQ_FAST);
  const bool eoPath = (ws_size >= REQ_EO);

  // zero routing scratch (incl. pad entries of assign_* -> token 0, weight 0)
  hipMemsetAsync(ws, 0, fast ? X0 : 336128, stream);
  if (!eoPath) {
    hipMemsetAsync(d_out, 0, (size_t)out_size * sizeof(float), stream);
  }

  gating_kernel<<<N_TOKENS / 4, 256, 0, stream>>>(x, gate_w, gate_b, counts,
                                                  tok_idx, tok_w, xb);
  finalize_routing<<<1, 1, 0, stream>>>(counts, offsets, out + (out_size - 1));

  if (fast) {
    scatter_kernel<<<N_TOKENS / 256, 256, 0, stream>>>(tok_idx, tok_w, offsets, cursors,
                                                       assign_token, assign_w, tok_pos);
    transpose_cvt_kernel<<<dim3(D_HIDDEN / 64, D_MODEL / 64, N_EXPERTS), 256, 0, stream>>>(
        w1, w1t, D_MODEL, D_HIDDEN);
    gemm1_kernel<<<dim3(ROWT, D_HIDDEN / 256), 256, 0, stream>>>(
        xb, w1t, b1, assign_token, offsets, hbuf);
    transpose_cvt_kernel<<<dim3(D_MODEL / 64, D_HIDDEN / 64, N_EXPERTS), 256, 0, stream>>>(
        w2, w2t, D_HIDDEN, D_MODEL);
    if (eoPath) {
      gemm2_kernel<true><<<dim3(ROWT, D_MODEL / 256), 256, 0, stream>>>(
          hbuf, w2t, b2, assign_token, assign_w, offsets, eo);
      combine_kernel<<<(N_TOKENS * D_MODEL) / 1024, 256, 0, stream>>>(eo, tok_pos, out);
    } else {
      gemm2_kernel<false><<<dim3(ROWT, D_MODEL / 256), 256, 0, stream>>>(
          hbuf, w2t, b2, assign_token, assign_w, offsets, out);
    }
  } else {
    moe_fallback_kernel<<<NASSIGN, 256, 0, stream>>>(x, w1, b1, w2, b2, tok_idx, tok_w, out);
  }
}

// Round 14
// 739.356 us; speedup vs baseline: 1.1993x; 1.0135x over previous
//
#include <hip/hip_runtime.h>

#define D_MODEL   1024
#define D_HIDDEN  4096
#define N_EXPERTS 8
#define N_TOKENS  8192
#define NASSIGN   (N_TOKENS * 2)               // 16384
#define PADCAP    (NASSIGN + N_EXPERTS * 128)  // 17408
#define ROWT      (PADCAP / 128)               // 136 = 8*17

typedef unsigned short u16;
typedef __bf16 bf16x8 __attribute__((ext_vector_type(8)));
typedef float  f32x4  __attribute__((ext_vector_type(4)));

__device__ __forceinline__ u16 f2bf(float f) {
  union { float f; unsigned u; } c; c.f = f;
  unsigned u = c.u;
  u = (u + 0x7fffu + ((u >> 16) & 1u)) >> 16;   // RNE
  return (u16)u;
}

__device__ __forceinline__ float bf2f(u16 v) {
  union { unsigned u; float f; } c; c.u = ((unsigned)v) << 16;
  return c.f;
}

__device__ __forceinline__ void async16(const void* g, void* l) {
  __builtin_amdgcn_global_load_lds(
      (const __attribute__((address_space(1))) unsigned int*)g,
      (__attribute__((address_space(3))) unsigned int*)l, 16, 0, 0);
}

// ---------------- gating (vectorized, fused x->bf16): 4 tokens/block ----------------
__global__ __launch_bounds__(256) void gating_kernel(
    const float* __restrict__ x, const float* __restrict__ gw,
    const float* __restrict__ gb, int* __restrict__ counts,
    int* __restrict__ tok_idx, float* __restrict__ tok_w,
    u16* __restrict__ xb)
{
  const int n = blockIdx.x * 4 + (threadIdx.x >> 6);
  const int lane = threadIdx.x & 63;
  const float4* x4 = (const float4*)x;
  const float4* gw4 = (const float4*)gw;

  float acc[8] = {0.f,0.f,0.f,0.f,0.f,0.f,0.f,0.f};
  #pragma unroll
  for (int cch = 0; cch < 4; ++cch) {
    const int f4i = cch * 64 + lane;                 // float4 index in row, 0..255
    float4 xv = x4[(size_t)n * 256 + f4i];

    uint2 o;
    o.x = (unsigned)f2bf(xv.x) | ((unsigned)f2bf(xv.y) << 16);
    o.y = (unsigned)f2bf(xv.z) | ((unsigned)f2bf(xv.w) << 16);
    *(uint2*)&xb[(size_t)n * D_MODEL + f4i * 4] = o;

    float xr[4] = {xv.x, xv.y, xv.z, xv.w};
    #pragma unroll
    for (int r = 0; r < 4; ++r) {
      int row = f4i * 4 + r;
      float4 g0 = gw4[row * 2], g1 = gw4[row * 2 + 1];   // gw is 32KB, L1/L2-hot
      acc[0] += xr[r] * g0.x; acc[1] += xr[r] * g0.y;
      acc[2] += xr[r] * g0.z; acc[3] += xr[r] * g0.w;
      acc[4] += xr[r] * g1.x; acc[5] += xr[r] * g1.y;
      acc[6] += xr[r] * g1.z; acc[7] += xr[r] * g1.w;
    }
  }
  for (int off = 32; off; off >>= 1)
    #pragma unroll
    for (int e = 0; e < 8; ++e) acc[e] += __shfl_xor(acc[e], off, 64);
  if (lane == 0) {
    float l[8], p[8];
    float m = -1e30f;
    for (int e = 0; e < 8; ++e) { l[e] = acc[e] + gb[e]; m = fmaxf(m, l[e]); }
    float s = 0.f;
    for (int e = 0; e < 8; ++e) { p[e] = expf(l[e] - m); s += p[e]; }
    float inv = 1.f / s;
    for (int e = 0; e < 8; ++e) p[e] *= inv;
    int i0 = 0;
    for (int e = 1; e < 8; ++e) if (p[e] > p[i0]) i0 = e;          // ties -> lowest idx
    int i1 = (i0 == 0) ? 1 : 0;
    for (int e = 0; e < 8; ++e) if (e != i0 && p[e] > p[i1]) i1 = e;
    tok_idx[2 * n]     = i0;  tok_idx[2 * n + 1] = i1;
    tok_w[2 * n]       = p[i0]; tok_w[2 * n + 1] = p[i1];
    atomicAdd(&counts[i0], 1);
    atomicAdd(&counts[i1], 1);
  }
}

// ---------------- offsets + load-balancing loss ----------------
__global__ void finalize_routing(const int* __restrict__ counts,
                                 int* __restrict__ offsets,
                                 float* __restrict__ out_loss)
{
  int off = 0;
  for (int e = 0; e < 8; ++e) {
    offsets[e] = off;
    off += ((counts[e] + 127) >> 7) << 7;   // 128-align each expert segment
  }
  offsets[8] = off;
  float loss = 0.f;
  for (int e = 0; e < 8; ++e) {
    float f = (float)counts[e] * (1.f / (float)NASSIGN);
    loss += f * f;
  }
  *out_loss = loss;
}

// ---------------- scatter tokens to expert segments ----------------
__global__ __launch_bounds__(256) void scatter_kernel(
    const int* __restrict__ tok_idx, const float* __restrict__ tok_w,
    const int* __restrict__ offsets, int* __restrict__ cursors,
    int* __restrict__ assign_token, float* __restrict__ assign_w,
    int* __restrict__ tok_pos)
{
  const int n = blockIdx.x * 256 + threadIdx.x;
  #pragma unroll
  for (int k = 0; k < 2; ++k) {
    int e = tok_idx[n * 2 + k];
    int pos = offsets[e] + atomicAdd(&cursors[e], 1);
    assign_token[pos] = n;
    assign_w[pos] = tok_w[n * 2 + k];
    tok_pos[n * 2 + k] = pos;
  }
}

// ------- transpose+convert: in[e][R][C] f32 -> out[e][C][R] bf16; tile 256R x 32C -------
// Writes 512B-contiguous per 32-lane group (vs 128B before).
__global__ __launch_bounds__(256) void transpose_cvt_kernel(
    const float* __restrict__ in, u16* __restrict__ out, int R, int C)
{
  const int e = blockIdx.z;
  const int c0 = blockIdx.x * 32, r0 = blockIdx.y * 256;
  __shared__ float tile[256][34];   // +2 pad: 2-way LDS alias (free)
  const int tid = threadIdx.x;
  const float* ip = in + (size_t)e * R * C;
  u16* op = out + (size_t)e * R * C;
  const int rr = tid >> 3, cc4 = (tid & 7) * 4;   // 32 rows/pass, 8 lanes x float4
  #pragma unroll
  for (int p = 0; p < 8; ++p) {
    int r = rr + p * 32;
    float4 v = *(const float4*)&ip[(size_t)(r0 + r) * C + c0 + cc4];
    tile[r][cc4 + 0] = v.x; tile[r][cc4 + 1] = v.y;
    tile[r][cc4 + 2] = v.z; tile[r][cc4 + 3] = v.w;
  }
  __syncthreads();
  const int c = tid >> 5, ch = tid & 31;          // 2 out-rows/pass, 32 chunks of 16B
  #pragma unroll
  for (int p = 0; p < 4; ++p) {
    int crow = c + p * 8;                         // 0..31... (c in {0,1}; 4 passes x 8)
    u16 buf[8];
    #pragma unroll
    for (int j = 0; j < 8; ++j) buf[j] = f2bf(tile[ch * 8 + j][crow]);
    *(uint4*)&op[(size_t)(c0 + crow) * R + r0 + ch * 8] = *(const uint4*)&buf[0];
  }
}

// ================== GEMM core (R13 config, unchanged) ==================
// BM=128, BN=256, BK=32. 4 waves, wave-tile 64x128. 3 cyclic LDS bufs (72KB),
// counted vmcnt(6), raw s_barrier. XCD-bijective rt swizzle (136 = 8*17).

// ---------------- GEMM1: h = relu(X_gathered @ w1[e] + b1[e]) ----------------
__global__ __launch_bounds__(256, 2) void gemm1_kernel(
    const u16* __restrict__ xb, const u16* __restrict__ w1t,
    const float* __restrict__ b1, const int* __restrict__ assign_token,
    const int* __restrict__ offsets, u16* __restrict__ hbuf)
{
  const int rt = (blockIdx.x & 7) * 17 + (blockIdx.x >> 3);   // XCD-bijective
  const int ct = blockIdx.y;   // ct in [0,16)
  if (rt * 128 >= offsets[8]) return;
  int e = 0;
  while (offsets[e + 1] <= rt * 128) ++e;

  __shared__ __align__(16) u16 smem[36864];
  u16* Asm = smem;            // [0, 12288)
  u16* Bsm = smem + 12288;    // [12288, 36864)

  const int tid = threadIdx.x;
  const int wave = tid >> 6, lane = tid & 63;

  const int ra0 = tid >> 2,         sa = tid & 3;
  const int ra1 = (tid + 256) >> 2;
  const int sga0 = sa ^ ((ra0 >> 1) & 3);
  const int sga1 = sa ^ ((ra1 >> 1) & 3);
  const long aBase0 = (long)assign_token[rt * 128 + ra0] * D_MODEL + sga0 * 8;
  const long aBase1 = (long)assign_token[rt * 128 + ra1] * D_MODEL + sga1 * 8;

  long bBase[4];
  #pragma unroll
  for (int k = 0; k < 4; ++k) {
    int c = tid + k * 256;
    int r = c >> 2, s = c & 3;
    int sg = s ^ ((r >> 1) & 3);
    bBase[k] = ((long)e * D_HIDDEN + ct * 256 + r) * D_MODEL + sg * 8;
  }

  const int wr = (wave >> 1) * 64;    // wave row base (0/64)
  const int wc = (wave & 1) * 128;    // wave col base (0/128)
  f32x4 acc[4][8];
  #pragma unroll
  for (int i = 0; i < 4; ++i)
    #pragma unroll
    for (int j = 0; j < 8; ++j) acc[i][j] = (f32x4){0.f, 0.f, 0.f, 0.f};

  int aoff[4], boff[8];
  #pragma unroll
  for (int i = 0; i < 4; ++i) {
    int row = wr + i * 16 + (lane & 15);
    aoff[i] = row * 32 + (((lane >> 4) ^ ((row >> 1) & 3)) * 8);
  }
  #pragma unroll
  for (int j = 0; j < 8; ++j) {
    int col = wc + j * 16 + (lane & 15);
    boff[j] = col * 32 + (((lane >> 4) ^ ((col >> 1) & 3)) * 8);
  }

  #define STAGE1(bi, k0) do { \
    u16* A_ = Asm + (bi) * 4096; \
    u16* B_ = Bsm + (bi) * 8192; \
    async16(xb  + aBase0   + (k0), A_ + wave * 512); \
    async16(xb  + aBase1   + (k0), A_ + 2048 + wave * 512); \
    async16(w1t + bBase[0] + (k0), B_ + wave * 512); \
    async16(w1t + bBase[1] + (k0), B_ + 2048 + wave * 512); \
    async16(w1t + bBase[2] + (k0), B_ + 4096 + wave * 512); \
    async16(w1t + bBase[3] + (k0), B_ + 6144 + wave * 512); \
  } while (0)

  const int NT = D_MODEL / 32;   // 32
  STAGE1(0, 0);
  STAGE1(1, 32);
  int bi = 0;
  for (int t = 0; t < NT; ++t) {
    if (t < NT - 1) asm volatile("s_waitcnt vmcnt(6)" ::: "memory");
    else            asm volatile("s_waitcnt vmcnt(0)" ::: "memory");
    __builtin_amdgcn_s_barrier();
    const u16* A = Asm + bi * 4096;
    const u16* B = Bsm + bi * 8192;
    bf16x8 a[4], b[8];
    #pragma unroll
    for (int i = 0; i < 4; ++i) a[i] = *(const bf16x8*)&A[aoff[i]];
    #pragma unroll
    for (int j = 0; j < 8; ++j) b[j] = *(const bf16x8*)&B[boff[j]];
    __builtin_amdgcn_s_setprio(1);
    #pragma unroll
    for (int i = 0; i < 4; ++i)
      #pragma unroll
      for (int j = 0; j < 8; ++j)
        acc[i][j] = __builtin_amdgcn_mfma_f32_16x16x32_bf16(a[i], b[j], acc[i][j], 0, 0, 0);
    __builtin_amdgcn_s_setprio(0);
    if (t + 2 < NT) {
      int nb = bi + 2; if (nb >= 3) nb -= 3;
      STAGE1(nb, (t + 2) * 32);
    }
    ++bi; if (bi == 3) bi = 0;
  }
  #undef STAGE1

  float bias[8];
  #pragma unroll
  for (int j = 0; j < 8; ++j)
    bias[j] = b1[(size_t)e * D_HIDDEN + ct * 256 + wc + j * 16 + (lane & 15)];

  __syncthreads();   // all LDS reads of staging bufs done before Hs overlay
  u16* Hs = smem;
  #pragma unroll
  for (int i = 0; i < 4; ++i)
    #pragma unroll
    for (int j = 0; j < 8; ++j)
      #pragma unroll
      for (int r = 0; r < 4; ++r) {
        int rl = wr + i * 16 + ((lane >> 4) * 4) + r;
        int cl = wc + j * 16 + (lane & 15);
        Hs[rl * 256 + cl] = f2bf(fmaxf(acc[i][j][r] + bias[j], 0.f));
      }
  __syncthreads();
  #pragma unroll
  for (int t = 0; t < 16; ++t) {
    int cc = tid + t * 256;
    int row = cc >> 5, cs = cc & 31;
    *(uint4*)&hbuf[((size_t)(rt * 128 + row)) * D_HIDDEN + ct * 256 + cs * 8] =
        *(const uint4*)&Hs[row * 256 + cs * 8];
  }
}

// ---------------- GEMM2: eo_bf16[pos] = w * (h @ w2[e] + b2[e])  (or atomic into out) ----
template <bool EO>
__global__ __launch_bounds__(256, 2) void gemm2_kernel(
    const u16* __restrict__ hbuf, const u16* __restrict__ w2t,
    const float* __restrict__ b2, const int* __restrict__ assign_token,
    const float* __restrict__ assign_w, const int* __restrict__ offsets,
    void* __restrict__ dstv)   // EO ? u16* eo : float* out
{
  const int rt = (blockIdx.x & 7) * 17 + (blockIdx.x >> 3);   // XCD-bijective
  const int ct = blockIdx.y;   // ct in [0,4)
  if (rt * 128 >= offsets[8]) return;
  int e = 0;
  while (offsets[e + 1] <= rt * 128) ++e;

  __shared__ __align__(16) u16 smem[36864];
  u16* Asm = smem;
  u16* Bsm = smem + 12288;
  __shared__ int tokS[128];
  __shared__ float wS[128];

  const int tid = threadIdx.x;
  const int wave = tid >> 6, lane = tid & 63;
  if (tid < 128) {
    tokS[tid] = assign_token[rt * 128 + tid];
    wS[tid] = assign_w[rt * 128 + tid];
  }

  const int ra0 = tid >> 2,         sa = tid & 3;
  const int ra1 = (tid + 256) >> 2;
  const int sga0 = sa ^ ((ra0 >> 1) & 3);
  const int sga1 = sa ^ ((ra1 >> 1) & 3);
  const long aBase0 = ((long)(rt * 128 + ra0)) * D_HIDDEN + sga0 * 8;
  const long aBase1 = ((long)(rt * 128 + ra1)) * D_HIDDEN + sga1 * 8;

  long bBase[4];
  #pragma unroll
  for (int k = 0; k < 4; ++k) {
    int c = tid + k * 256;
    int r = c >> 2, s = c & 3;
    int sg = s ^ ((r >> 1) & 3);
    bBase[k] = ((long)e * D_MODEL + ct * 256 + r) * D_HIDDEN + sg * 8;
  }

  const int wr = (wave >> 1) * 64;
  const int wc = (wave & 1) * 128;
  f32x4 acc[4][8];
  #pragma unroll
  for (int i = 0; i < 4; ++i)
    #pragma unroll
    for (int j = 0; j < 8; ++j) acc[i][j] = (f32x4){0.f, 0.f, 0.f, 0.f};

  int aoff[4], boff[8];
  #pragma unroll
  for (int i = 0; i < 4; ++i) {
    int row = wr + i * 16 + (lane & 15);
    aoff[i] = row * 32 + (((lane >> 4) ^ ((row >> 1) & 3)) * 8);
  }
  #pragma unroll
  for (int j = 0; j < 8; ++j) {
    int col = wc + j * 16 + (lane & 15);
    boff[j] = col * 32 + (((lane >> 4) ^ ((col >> 1) & 3)) * 8);
  }

  #define STAGE2(bi, k0) do { \
    u16* A_ = Asm + (bi) * 4096; \
    u16* B_ = Bsm + (bi) * 8192; \
    async16(hbuf + aBase0   + (k0), A_ + wave * 512); \
    async16(hbuf + aBase1   + (k0), A_ + 2048 + wave * 512); \
    async16(w2t  + bBase[0] + (k0), B_ + wave * 512); \
    async16(w2t  + bBase[1] + (k0), B_ + 2048 + wave * 512); \
    async16(w2t  + bBase[2] + (k0), B_ + 4096 + wave * 512); \
    async16(w2t  + bBase[3] + (k0), B_ + 6144 + wave * 512); \
  } while (0)

  const int NT = D_HIDDEN / 32;   // 128
  STAGE2(0, 0);
  STAGE2(1, 32);
  int bi = 0;
  for (int t = 0; t < NT; ++t) {
    if (t < NT - 1) asm volatile("s_waitcnt vmcnt(6)" ::: "memory");
    else            asm volatile("s_waitcnt vmcnt(0)" ::: "memory");
    __builtin_amdgcn_s_barrier();
    const u16* A = Asm + bi * 4096;
    const u16* B = Bsm + bi * 8192;
    bf16x8 a[4], b[8];
    #pragma unroll
    for (int i = 0; i < 4; ++i) a[i] = *(const bf16x8*)&A[aoff[i]];
    #pragma unroll
    for (int j = 0; j < 8; ++j) b[j] = *(const bf16x8*)&B[boff[j]];
    __builtin_amdgcn_s_setprio(1);
    #pragma unroll
    for (int i = 0; i < 4; ++i)
      #pragma unroll
      for (int j = 0; j < 8; ++j)
        acc[i][j] = __builtin_amdgcn_mfma_f32_16x16x32_bf16(a[i], b[j], acc[i][j], 0, 0, 0);
    __builtin_amdgcn_s_setprio(0);
    if (t + 2 < NT) {
      int nb = bi + 2; if (nb >= 3) nb -= 3;
      STAGE2(nb, (t + 2) * 32);
    }
    ++bi; if (bi == 3) bi = 0;
  }
  #undef STAGE2

  float bias[8];
  #pragma unroll
  for (int j = 0; j < 8; ++j)
    bias[j] = b2[(size_t)e * D_MODEL + ct * 256 + wc + j * 16 + (lane & 15)];

  #pragma unroll
  for (int i = 0; i < 4; ++i)
    #pragma unroll
    for (int r = 0; r < 4; ++r) {
      int rl = wr + i * 16 + ((lane >> 4) * 4) + r;
      float wgt = wS[rl];
      if (EO) {
        u16* dst = (u16*)dstv;
        size_t row = (size_t)(rt * 128 + rl);
        #pragma unroll
        for (int j = 0; j < 8; ++j) {
          float v = (acc[i][j][r] + bias[j]) * wgt;
          dst[row * D_MODEL + ct * 256 + wc + j * 16 + (lane & 15)] = f2bf(v);
        }
      } else {
        float* dst = (float*)dstv;
        int tok = tokS[rl];
        #pragma unroll
        for (int j = 0; j < 8; ++j) {
          float v = (acc[i][j][r] + bias[j]) * wgt;
          atomicAdd(&dst[(size_t)tok * D_MODEL + ct * 256 + wc + j * 16 + (lane & 15)], v);
        }
      }
    }
}

// ---------------- combine: out[n] = eo_bf16[pos0] + eo_bf16[pos1] ----------------
__global__ __launch_bounds__(256) void combine_kernel(
    const u16* __restrict__ eo, const int* __restrict__ tok_pos,
    float* __restrict__ out)
{
  int idx = blockIdx.x * 256 + threadIdx.x;   // one float4 (4 values) per thread
  int n = idx >> 8;                           // 256 chunks per token
  int c = (idx & 255) * 4;
  int p0 = tok_pos[2 * n], p1 = tok_pos[2 * n + 1];
  uint2 ua = *(const uint2*)&eo[(size_t)p0 * D_MODEL + c];
  uint2 ub = *(const uint2*)&eo[(size_t)p1 * D_MODEL + c];
  float4 o;
  o.x = bf2f((u16)(ua.x & 0xffff))  + bf2f((u16)(ub.x & 0xffff));
  o.y = bf2f((u16)(ua.x >> 16))     + bf2f((u16)(ub.x >> 16));
  o.z = bf2f((u16)(ua.y & 0xffff))  + bf2f((u16)(ub.y & 0xffff));
  o.w = bf2f((u16)(ua.y >> 16))     + bf2f((u16)(ub.y >> 16));
  *(float4*)&out[(size_t)n * D_MODEL + c] = o;
}

// ---------------- fallback (tiny ws): naive fp32 per-assignment ----------------
__global__ __launch_bounds__(256) void moe_fallback_kernel(
    const float* __restrict__ x, const float* __restrict__ w1,
    const float* __restrict__ b1, const float* __restrict__ w2,
    const float* __restrict__ b2, const int* __restrict__ tok_idx,
    const float* __restrict__ tok_w, float* __restrict__ out)
{
  const int a = blockIdx.x;
  const int n = a >> 1, slot = a & 1;
  const int e = tok_idx[n * 2 + slot];
  const float wgt = tok_w[n * 2 + slot];
  __shared__ float xs[D_MODEL];
  __shared__ float hs[D_HIDDEN];
  const int tid = threadIdx.x;
  for (int d = tid; d < D_MODEL; d += 256) xs[d] = x[(size_t)n * D_MODEL + d];
  __syncthreads();
  for (int h = tid; h < D_HIDDEN; h += 256) {
    float acc = b1[(size_t)e * D_HIDDEN + h];
    for (int d = 0; d < D_MODEL; ++d)
      acc += xs[d] * w1[((size_t)e * D_MODEL + d) * D_HIDDEN + h];
    hs[h] = fmaxf(acc, 0.f);
  }
  __syncthreads();
  for (int d = tid; d < D_MODEL; d += 256) {
    float acc = b2[(size_t)e * D_MODEL + d];
    for (int h = 0; h < D_HIDDEN; ++h)
      acc += hs[h] * w2[((size_t)e * D_HIDDEN + h) * D_MODEL + d];
    atomicAdd(&out[(size_t)n * D_MODEL + d], wgt * acc);
  }
}

extern "C" void kernel_launch(void* const* d_in, const int* in_sizes, int n_in,
                              void* d_out, int out_size, void* d_ws, size_t ws_size,
                              hipStream_t stream) {
  const float* x      = (const float*)d_in[0];
  const float* gate_w = (const float*)d_in[1];
  const float* gate_b = (const float*)d_in[2];
  const float* w1     = (const float*)d_in[3];
  const float* b1     = (const float*)d_in[4];
  const float* w2     = (const float*)d_in[5];
  const float* b2     = (const float*)d_in[6];
  float* out = (float*)d_out;

  char* ws = (char*)d_ws;
  int*   counts       = (int*)(ws + 0);
  int*   cursors      = (int*)(ws + 32);
  int*   offsets      = (int*)(ws + 64);
  int*   tok_idx      = (int*)(ws + 256);       // 64 KB
  float* tok_w        = (float*)(ws + 65792);   // 64 KB
  int*   tok_pos      = (int*)(ws + 131328);    // 64 KB
  int*   assign_token = (int*)(ws + 196864);    // 68 KB
  float* assign_w     = (float*)(ws + 266496);  // 68 KB
  const size_t X0 = 336128;
  u16* xb   = (u16*)(ws + X0);
  u16* w1t  = (u16*)(ws + X0 + 16777216);
  u16* w2t  = (u16*)(ws + X0);                  // aliases xb+w1t (dead after GEMM1)
  u16* hbuf = (u16*)(ws + X0 + 83886080);
  u16* eo   = (u16*)(ws + X0 + 226492416ull);   // [PADCAP][1024] bf16 (no w1t overlap)
  const size_t REQ_FAST = X0 + 226492416ull;                 // ~216 MiB
  const size_t REQ_EO   = REQ_FAST + 35651584ull;            // ~250 MiB

  const bool fast = (ws_size >= REQ_FAST);
  const bool eoPath = (ws_size >= REQ_EO);

  // zero routing scratch (incl. pad entries of assign_* -> token 0, weight 0)
  hipMemsetAsync(ws, 0, fast ? X0 : 336128, stream);
  if (!eoPath) {
    hipMemsetAsync(d_out, 0, (size_t)out_size * sizeof(float), stream);
  }

  gating_kernel<<<N_TOKENS / 4, 256, 0, stream>>>(x, gate_w, gate_b, counts,
                                                  tok_idx, tok_w, xb);
  finalize_routing<<<1, 1, 0, stream>>>(counts, offsets, out + (out_size - 1));

  if (fast) {
    scatter_kernel<<<N_TOKENS / 256, 256, 0, stream>>>(tok_idx, tok_w, offsets, cursors,
                                                       assign_token, assign_w, tok_pos);
    transpose_cvt_kernel<<<dim3(D_HIDDEN / 32, D_MODEL / 256, N_EXPERTS), 256, 0, stream>>>(
        w1, w1t, D_MODEL, D_HIDDEN);
    gemm1_kernel<<<dim3(ROWT, D_HIDDEN / 256), 256, 0, stream>>>(
        xb, w1t, b1, assign_token, offsets, hbuf);
    transpose_cvt_kernel<<<dim3(D_MODEL / 32, D_HIDDEN / 256, N_EXPERTS), 256, 0, stream>>>(
        w2, w2t, D_HIDDEN, D_MODEL);
    if (eoPath) {
      gemm2_kernel<true><<<dim3(ROWT, D_MODEL / 256), 256, 0, stream>>>(
          hbuf, w2t, b2, assign_token, assign_w, offsets, eo);
      combine_kernel<<<(N_TOKENS * D_MODEL) / 1024, 256, 0, stream>>>(eo, tok_pos, out);
    } else {
      gemm2_kernel<false><<<dim3(ROWT, D_MODEL / 256), 256, 0, stream>>>(
          hbuf, w2t, b2, assign_token, assign_w, offsets, out);
    }
  } else {
    moe_fallback_kernel<<<NASSIGN, 256, 0, stream>>>(x, w1, b1, w2, b2, tok_idx, tok_w, out);
  }
}